// Round 20
// baseline (2741.990 us; speedup 1.0000x reference)
//
#include <hip/hip_runtime.h>
#include <cstdint>
#include <cstddef>

typedef __bf16 bf16x8 __attribute__((ext_vector_type(8)));
typedef float f32x4 __attribute__((ext_vector_type(4)));
typedef float f32x4v __attribute__((ext_vector_type(4)));

static __device__ __forceinline__ f32x4 mfma16(bf16x8 a, bf16x8 b, f32x4 c) {
  return __builtin_amdgcn_mfma_f32_16x16x32_bf16(a, b, c, 0, 0, 0);
}

// LAW (R19 forensics): compute kernels must NEVER vector-load from d_in —
// d_in is only touched by scalar converter kernels; all bf16x8 loads hit ws.

// ---------------- input dtype sniffing (proven) ----------------
__global__ __launch_bounds__(256) void detect_k(const uint32_t* __restrict__ hs,
                                                int* __restrict__ flag) {
  __shared__ int cnt;
  if (threadIdx.x == 0) cnt = 0;
  __syncthreads();
  uint32_t w = hs[threadIdx.x];
  int b = (w >> 8) & 0x7F;
  if (b >= 0x3C && b <= 0x40) atomicAdd(&cnt, 1);
  __syncthreads();
  if (threadIdx.x == 0) *flag = (cnt >= 128) ? 1 : 0;
}

// ---------------- dtype-adaptive converters (proven; SCALAR d_in reads) ----------
__global__ __launch_bounds__(256) void cvt_to_bf16_k(const void* __restrict__ src,
                                                     __bf16* __restrict__ dst, int n,
                                                     const int* __restrict__ flag) {
  int i = blockIdx.x * 256 + threadIdx.x;
  if (i >= n) return;
  float v = (*flag) ? (float)((const __bf16*)src)[i] : ((const float*)src)[i];
  dst[i] = (__bf16)v;
}

__global__ __launch_bounds__(256) void cvt_to_f32_k(const void* __restrict__ src,
                                                    float* __restrict__ dst, int n,
                                                    const int* __restrict__ flag) {
  int i = blockIdx.x * 256 + threadIdx.x;
  if (i >= n) return;
  dst[i] = (*flag) ? (float)((const __bf16*)src)[i] : ((const float*)src)[i];
}

// ---------------- sgemm64 (R16/R18-proven): vectorized staging, z-fused -----------
__global__ __launch_bounds__(256) void sgemm64_k(const __bf16* __restrict__ A,
                                                 const __bf16* __restrict__ B,
                                                 const float* __restrict__ bias,
                                                 __bf16* __restrict__ C,
                                                 int M, int N, int K, int ldc, int coloff) {
  __shared__ float As[16][65];
  __shared__ float Bs[16][65];
  const int tx = threadIdx.x, ty = threadIdx.y;
  const int tid = ty * 16 + tx;
  const int z = blockIdx.z;
  const __bf16* Bz = B + (size_t)z * 1048576;
  const float* biasz = bias + z * 1024;
  const int coloffz = coloff + z * 1024;
  const int m0 = blockIdx.x * 64, n0 = blockIdx.y * 64;
  float acc[4][4] = {};
  for (int kt = 0; kt < K; kt += 16) {
    if (tid < 128) {
      int ml = tid >> 1, half = tid & 1;
      bf16x8 av = *(const bf16x8*)(A + (size_t)(m0 + ml) * K + kt + half * 8);
#pragma unroll
      for (int j = 0; j < 8; ++j) As[half * 8 + j][ml] = (float)av[j];
    } else {
      int t2 = tid - 128;
      int kk = t2 >> 3, seg = t2 & 7;
      bf16x8 bv = *(const bf16x8*)(Bz + (size_t)(kt + kk) * N + n0 + seg * 8);
#pragma unroll
      for (int j = 0; j < 8; ++j) Bs[kk][seg * 8 + j] = (float)bv[j];
    }
    __syncthreads();
#pragma unroll
    for (int kk = 0; kk < 16; ++kk) {
      float a[4], b[4];
#pragma unroll
      for (int i = 0; i < 4; ++i) a[i] = As[kk][ty * 4 + i];
#pragma unroll
      for (int i = 0; i < 4; ++i) b[i] = Bs[kk][tx * 4 + i];
#pragma unroll
      for (int i = 0; i < 4; ++i)
#pragma unroll
        for (int j = 0; j < 4; ++j) acc[i][j] += a[i] * b[j];
    }
    __syncthreads();
  }
#pragma unroll
  for (int i = 0; i < 4; ++i) {
    int row = m0 + ty * 4 + i;
#pragma unroll
    for (int j = 0; j < 4; ++j) {
      int col = n0 + tx * 4 + j;
      C[(size_t)row * ldc + coloffz + col] = (__bf16)(acc[i][j] + biasz[col]);
    }
  }
}

__global__ __launch_bounds__(256) void sgemm64_out_k(const __bf16* __restrict__ A,
                                                     const __bf16* __restrict__ B,
                                                     const float* __restrict__ bias,
                                                     void* __restrict__ out,
                                                     int M, int N, int K,
                                                     const int* __restrict__ flag) {
  __shared__ float As[16][65];
  __shared__ float Bs[16][65];
  const int tx = threadIdx.x, ty = threadIdx.y;
  const int tid = ty * 16 + tx;
  const int m0 = blockIdx.x * 64, n0 = blockIdx.y * 64;
  float acc[4][4] = {};
  for (int kt = 0; kt < K; kt += 16) {
    if (tid < 128) {
      int ml = tid >> 1, half = tid & 1;
      bf16x8 av = *(const bf16x8*)(A + (size_t)(m0 + ml) * K + kt + half * 8);
#pragma unroll
      for (int j = 0; j < 8; ++j) As[half * 8 + j][ml] = (float)av[j];
    } else {
      int t2 = tid - 128;
      int kk = t2 >> 3, seg = t2 & 7;
      bf16x8 bv = *(const bf16x8*)(B + (size_t)(kt + kk) * N + n0 + seg * 8);
#pragma unroll
      for (int j = 0; j < 8; ++j) Bs[kk][seg * 8 + j] = (float)bv[j];
    }
    __syncthreads();
#pragma unroll
    for (int kk = 0; kk < 16; ++kk) {
      float a[4], b[4];
#pragma unroll
      for (int i = 0; i < 4; ++i) a[i] = As[kk][ty * 4 + i];
#pragma unroll
      for (int i = 0; i < 4; ++i) b[i] = Bs[kk][tx * 4 + i];
#pragma unroll
      for (int i = 0; i < 4; ++i)
#pragma unroll
        for (int j = 0; j < 4; ++j) acc[i][j] += a[i] * b[j];
    }
    __syncthreads();
  }
  int use16 = *flag;
#pragma unroll
  for (int i = 0; i < 4; ++i) {
    int row = m0 + ty * 4 + i;
#pragma unroll
    for (int j = 0; j < 4; ++j) {
      int col = n0 + tx * 4 + j;
      float r = acc[i][j] + bias[col];
      size_t idx = (size_t)row * N + col;
      if (use16) ((__bf16*)out)[idx] = (__bf16)r;
      else       ((float*)out)[idx] = r;
    }
  }
}

// ---------------- MFMA GEMM (R8 pattern) — DEAD-OUTPUT PROBE, ws-only inputs ------
__global__ __launch_bounds__(256) void gemm_nt_k(const __bf16* __restrict__ A,
                                                 const __bf16* __restrict__ B,
                                                 const float* __restrict__ bias,
                                                 __bf16* __restrict__ C,
                                                 int M, int N, int K, int ldc, int coloff) {
  const int tm = blockIdx.x * 128, tn = blockIdx.y * 128;
  const int tid = threadIdx.x;
  const int w = tid >> 6, l = tid & 63;
  const int l15 = l & 15, l4 = l >> 4;
  const int wm = (w >> 1) * 64, wn = (w & 1) * 64;
  __shared__ __bf16 As[128][72];
  __shared__ __bf16 Bs[128][72];
  f32x4 acc[4][4] = {};
  for (int kt = 0; kt < K; kt += 64) {
    __syncthreads();
#pragma unroll
    for (int i = 0; i < 4; ++i) {
      int c = tid + i * 256;
      int r = c >> 3, s = (c & 7) * 8;
      *(bf16x8*)(&As[r][s]) = *(const bf16x8*)(A + (size_t)(tm + r) * K + kt + s);
    }
#pragma unroll
    for (int i = 0; i < 4; ++i) {
      int c = tid + i * 256;
      int kr = c >> 4, nc = (c & 15) * 8;
      bf16x8 bv = *(const bf16x8*)(B + (size_t)(kt + kr) * N + tn + nc);
#pragma unroll
      for (int j = 0; j < 8; ++j) Bs[nc + j][kr] = bv[j];
    }
    __syncthreads();
#pragma unroll
    for (int kk = 0; kk < 2; ++kk) {
      bf16x8 af[4], bfr[4];
#pragma unroll
      for (int m = 0; m < 4; ++m)
        af[m] = *(const bf16x8*)(&As[wm + m * 16 + l15][kk * 32 + l4 * 8]);
#pragma unroll
      for (int n = 0; n < 4; ++n)
        bfr[n] = *(const bf16x8*)(&Bs[wn + n * 16 + l15][kk * 32 + l4 * 8]);
#pragma unroll
      for (int m = 0; m < 4; ++m)
#pragma unroll
        for (int n = 0; n < 4; ++n)
          acc[m][n] = mfma16(af[m], bfr[n], acc[m][n]);
    }
  }
#pragma unroll
  for (int m = 0; m < 4; ++m)
#pragma unroll
    for (int n = 0; n < 4; ++n) {
      int row = tm + wm + m * 16 + l4 * 4;
      int col = tn + wn + n * 16 + l15;
      float bb = bias[col];
#pragma unroll
      for (int r = 0; r < 4; ++r)
        C[(size_t)(row + r) * ldc + coloff + col] = (__bf16)(acc[m][n][r] + bb);
    }
}

// ---------------- V transpose (proven) ----------------
__global__ __launch_bounds__(256) void vt_k(const __bf16* __restrict__ QKVb,
                                            __bf16* __restrict__ Vt) {
  __shared__ __bf16 t[64][72];
  const int h = blockIdx.x, k0 = blockIdx.y * 64;
  const int tid = threadIdx.x;
  const int r = tid >> 2, dc = (tid & 3) * 16;
  const __bf16* src = QKVb + (size_t)(k0 + r) * 3072 + 2048 + h * 64 + dc;
  *(bf16x8*)(&t[r][dc]) = *(const bf16x8*)(src);
  *(bf16x8*)(&t[r][dc + 8]) = *(const bf16x8*)(src + 8);
  __syncthreads();
  const int dr = tid >> 2, kc = (tid & 3) * 16;
  __bf16* dst = Vt + ((size_t)(h * 64 + dr)) * 1024 + k0 + kc;
  bf16x8 o0, o1;
#pragma unroll
  for (int j = 0; j < 8; ++j) { o0[j] = t[kc + j][dr]; o1[j] = t[kc + 8 + j][dr]; }
  *(bf16x8*)dst = o0;
  *(bf16x8*)(dst + 8) = o1;
}

// ---------------- attention v10: f32 Q LDS + qq-paired score (rel16 from ws) -------
// Same partial-sum reassociation as R18's v9 (p[c&3], tree sum) -> same output.
__global__ __launch_bounds__(256) void attn_v10_k(const __bf16* __restrict__ QKV,
                                                  const __bf16* __restrict__ Vt,
                                                  const float* __restrict__ amask,
                                                  const __bf16* __restrict__ rel16,
                                                  const float* __restrict__ Mg,
                                                  const float* __restrict__ zg,
                                                  const float* __restrict__ ga,
                                                  __bf16* __restrict__ comb) {
  const int q0 = blockIdx.x * 4, h = blockIdx.y;
  const int tid = threadIdx.x;
  __shared__ float sc[4][1024];
  __shared__ float qsf[4][64];
  __shared__ f32x4v red4[256];
  __shared__ float ov[4][4][64];
  __shared__ float sq_s[4][64];

  {
    int qq = tid >> 6, d = tid & 63;
    qsf[qq][d] = (float)QKV[(size_t)(q0 + qq) * 3072 + h * 64 + d];
  }
  __syncthreads();

#pragma unroll 1
  for (int jj = 0; jj < 4; ++jj) {
    int k = tid + jj * 256;
    const __bf16* kp = QKV + (size_t)k * 3072 + 1024 + h * 64;
    bf16x8 kv[8];
#pragma unroll
    for (int c = 0; c < 8; ++c) kv[c] = *(const bf16x8*)(kp + c * 8);
    float mk = amask[k] * (-1e9f);
    const __bf16* rbase = rel16 + (size_t)(q0 - k + 1024) * 64;
#pragma unroll 1
    for (int qq = 0; qq < 4; qq += 2) {
      const __bf16* rp0 = rbase + (size_t)qq * 64;
      float p0[4] = {0.f, 0.f, 0.f, 0.f};
      float p1[4] = {0.f, 0.f, 0.f, 0.f};
#pragma unroll
      for (int c = 0; c < 8; ++c) {
        bf16x8 r0 = *(const bf16x8*)(rp0 + c * 8);
        bf16x8 r1 = *(const bf16x8*)(rp0 + 64 + c * 8);
        const float* q0p = &qsf[qq][c * 8];
        const float* q1p = &qsf[qq + 1][c * 8];
#pragma unroll
        for (int e = 0; e < 8; ++e) {
          float kf = (float)kv[c][e];
          p0[c & 3] += (q0p[e] + (float)r0[e]) * kf;
          p1[c & 3] += (q1p[e] + (float)r1[e]) * kf;
        }
      }
      sc[qq][k]     = ((p0[0] + p0[1]) + (p0[2] + p0[3])) * 0.125f + mk;
      sc[qq + 1][k] = ((p1[0] + p1[1]) + (p1[2] + p1[3])) * 0.125f + mk;
    }
  }
  __syncthreads();

  f32x4v mx;
  mx[0] = mx[1] = mx[2] = mx[3] = -3.0e38f;
  for (int k = tid; k < 1024; k += 256) {
    mx[0] = fmaxf(mx[0], sc[0][k]);
    mx[1] = fmaxf(mx[1], sc[1][k]);
    mx[2] = fmaxf(mx[2], sc[2][k]);
    mx[3] = fmaxf(mx[3], sc[3][k]);
  }
  red4[tid] = mx;
  __syncthreads();
  for (int s = 128; s > 0; s >>= 1) {
    if (tid < s) {
      f32x4v a = red4[tid], b = red4[tid + s];
      a[0] = fmaxf(a[0], b[0]); a[1] = fmaxf(a[1], b[1]);
      a[2] = fmaxf(a[2], b[2]); a[3] = fmaxf(a[3], b[3]);
      red4[tid] = a;
    }
    __syncthreads();
  }
  f32x4v mrow = red4[0];
  __syncthreads();

  f32x4v lp = {0.f, 0.f, 0.f, 0.f};
  for (int k = tid; k < 1024; k += 256) {
    float e0 = __expf(sc[0][k] - mrow[0]); sc[0][k] = e0; lp[0] += e0;
    float e1 = __expf(sc[1][k] - mrow[1]); sc[1][k] = e1; lp[1] += e1;
    float e2 = __expf(sc[2][k] - mrow[2]); sc[2][k] = e2; lp[2] += e2;
    float e3 = __expf(sc[3][k] - mrow[3]); sc[3][k] = e3; lp[3] += e3;
  }
  red4[tid] = lp;
  __syncthreads();
  for (int s = 128; s > 0; s >>= 1) {
    if (tid < s) {
      f32x4v a = red4[tid], b = red4[tid + s];
      a[0] += b[0]; a[1] += b[1]; a[2] += b[2]; a[3] += b[3];
      red4[tid] = a;
    }
    __syncthreads();
  }
  f32x4v lsum = red4[0];

  const int d = tid & 63, w4 = tid >> 6;
  float o0 = 0.f, o1 = 0.f, o2 = 0.f, o3 = 0.f;
  const __bf16* vrow = Vt + ((size_t)(h * 64 + d)) * 1024 + w4 * 256;
#pragma unroll 4
  for (int c = 0; c < 32; ++c) {
    bf16x8 vv = *(const bf16x8*)(vrow + c * 8);
    int k0 = w4 * 256 + c * 8;
#pragma unroll
    for (int e = 0; e < 8; ++e) {
      float v = (float)vv[e];
      o0 += sc[0][k0 + e] * v;
      o1 += sc[1][k0 + e] * v;
      o2 += sc[2][k0 + e] * v;
      o3 += sc[3][k0 + e] * v;
    }
  }
  ov[w4][0][d] = o0; ov[w4][1][d] = o1; ov[w4][2][d] = o2; ov[w4][3][d] = o3;
  __syncthreads();

  {
    int qq = tid >> 6, dd = tid & 63;
    float x = qsf[qq][dd];
    sq_s[qq][dd] = x > 0.f ? x + 1.f : __expf(x);
  }
  __syncthreads();

  {
    int qq = tid >> 6, d2 = tid & 63;
    float local = (ov[0][qq][d2] + ov[1][qq][d2] + ov[2][qq][d2] + ov[3][qq][d2]) /
                  lsum[qq];
    float num = 0.f, den = 1e-6f;
#pragma unroll
    for (int dd = 0; dd < 64; ++dd) {
      float sqv = sq_s[qq][dd];
      num += sqv * Mg[(size_t)h * 4096 + dd * 64 + d2];
      den += sqv * zg[h * 64 + dd];
    }
    float gate = 1.f / (1.f + __expf(-ga[0]));
    float cv = gate * local + (1.f - gate) * num / den;
    comb[(size_t)(q0 + qq) * 1024 + h * 64 + d2] = (__bf16)cv;
  }
}

// ---------------- launcher ----------------
extern "C" void kernel_launch(void* const* d_in, const int* in_sizes, int n_in,
                              void* d_out, int out_size, void* d_ws, size_t ws_size,
                              hipStream_t stream) {
  const int expect[14] = {4194304, 4096, 1048576, 1024, 1048576, 1024, 1048576,
                          1024, 1048576, 1024, 131136, 65536, 1024, 1};
  if (n_in != 14) return;
  for (int i = 0; i < 14; ++i)
    if (in_sizes[i] != expect[i]) return;

  char* ws = (char*)d_ws;
  int*    flag  = (int*)ws;                      // 4B
  float*  am32  = (float*)(ws + 1024);           // [4096]
  float*  b32   = (float*)(ws + 17408);          // bq|bk|bv|bo  [4][1024]
  float*  zg32  = (float*)(ws + 33792);          // [1024]
  float*  ga32  = (float*)(ws + 37888);          // [1]
  float*  Mg32  = (float*)(ws + 38912);          // [65536]
  __bf16* rel16 = (__bf16*)(ws + 301056);        // [131136]
  __bf16* hs16  = (__bf16*)(ws + 565248);        // [4096][1024]
  __bf16* W16   = (__bf16*)(ws + 8953856);       // 4x [1024][1024] (q,k,v,o)
  __bf16* qkv_b = (__bf16*)(ws + 17342464);      // [1024][3072]
  __bf16* comb  = (__bf16*)(ws + 23633920);      // [4096][1024]  ends 32022528
  __bf16* Vt    = (__bf16*)(ws + 32022528);      // [16][64][1024] ends 34119680
  __bf16* probeC = (__bf16*)(ws + 34119680);     // [1024][1024] dead, ends 36216832

  const bool doProbe = (ws_size >= 36216832);

  detect_k<<<1, 256, 0, stream>>>((const uint32_t*)d_in[0], flag);

  cvt_to_bf16_k<<<16384, 256, 0, stream>>>(d_in[0], hs16, 4194304, flag);
  cvt_to_f32_k<<<16, 256, 0, stream>>>(d_in[1], am32, 4096, flag);
  const int widx[4] = {2, 4, 6, 8};
  for (int j = 0; j < 4; ++j) {
    cvt_to_bf16_k<<<4096, 256, 0, stream>>>(d_in[widx[j]], W16 + (size_t)j * 1048576,
                                            1048576, flag);
    cvt_to_f32_k<<<4, 256, 0, stream>>>(d_in[widx[j] + 1], b32 + j * 1024, 1024, flag);
  }
  cvt_to_bf16_k<<<513, 256, 0, stream>>>(d_in[10], rel16, 131136, flag);
  cvt_to_f32_k<<<256, 256, 0, stream>>>(d_in[11], Mg32, 65536, flag);
  cvt_to_f32_k<<<4, 256, 0, stream>>>(d_in[12], zg32, 1024, flag);
  cvt_to_f32_k<<<1, 256, 0, stream>>>(d_in[13], ga32, 1, flag);

  // Law-A/Law-B discriminator: MFMA GEMM, ws-only inputs, dead output.
  if (doProbe)
    gemm_nt_k<<<dim3(8, 8), 256, 0, stream>>>(hs16, W16, b32, probeC,
                                              1024, 1024, 1024, 1024, 0);

  for (int b = 0; b < 4; ++b) {
    sgemm64_k<<<dim3(16, 16, 3), dim3(16, 16), 0, stream>>>(
        hs16 + (size_t)b * 1048576, W16, b32, qkv_b, 1024, 1024, 1024, 3072, 0);
    vt_k<<<dim3(16, 16), 256, 0, stream>>>(qkv_b, Vt);
    attn_v10_k<<<dim3(256, 16), 256, 0, stream>>>(
        qkv_b, Vt, am32 + b * 1024, rel16, Mg32, zg32, ga32,
        comb + (size_t)b * 1048576);
  }

  sgemm64_out_k<<<dim3(64, 16), dim3(16, 16), 0, stream>>>(
      comb, W16 + 3 * 1048576, b32 + 3 * 1024, d_out, 4096, 1024, 1024, flag);
}

// Round 21
// 1893.579 us; speedup vs baseline: 1.4480x; 1.4480x over previous
//
#include <hip/hip_runtime.h>
#include <cstdint>
#include <cstddef>

typedef __bf16 bf16x8 __attribute__((ext_vector_type(8)));
typedef float f32x4 __attribute__((ext_vector_type(4)));
typedef float f32x4v __attribute__((ext_vector_type(4)));

static __device__ __forceinline__ f32x4 mfma16(bf16x8 a, bf16x8 b, f32x4 c) {
  return __builtin_amdgcn_mfma_f32_16x16x32_bf16(a, b, c, 0, 0, 0);
}

// LAW (R19/R20 proven): compute kernels must NEVER vector-load from d_in —
// d_in is only touched by scalar converter kernels; all bf16x8 loads hit ws.
// MFMA validated safe+correct with ws inputs (R20 probe + R9 value check).

// ---------------- input dtype sniffing (proven) ----------------
__global__ __launch_bounds__(256) void detect_k(const uint32_t* __restrict__ hs,
                                                int* __restrict__ flag) {
  __shared__ int cnt;
  if (threadIdx.x == 0) cnt = 0;
  __syncthreads();
  uint32_t w = hs[threadIdx.x];
  int b = (w >> 8) & 0x7F;
  if (b >= 0x3C && b <= 0x40) atomicAdd(&cnt, 1);
  __syncthreads();
  if (threadIdx.x == 0) *flag = (cnt >= 128) ? 1 : 0;
}

// ---------------- dtype-adaptive converters (proven; SCALAR d_in reads) ----------
__global__ __launch_bounds__(256) void cvt_to_bf16_k(const void* __restrict__ src,
                                                     __bf16* __restrict__ dst, int n,
                                                     const int* __restrict__ flag) {
  int i = blockIdx.x * 256 + threadIdx.x;
  if (i >= n) return;
  float v = (*flag) ? (float)((const __bf16*)src)[i] : ((const float*)src)[i];
  dst[i] = (__bf16)v;
}

__global__ __launch_bounds__(256) void cvt_to_f32_k(const void* __restrict__ src,
                                                    float* __restrict__ dst, int n,
                                                    const int* __restrict__ flag) {
  int i = blockIdx.x * 256 + threadIdx.x;
  if (i >= n) return;
  dst[i] = (*flag) ? (float)((const __bf16*)src)[i] : ((const float*)src)[i];
}

// ---------------- MFMA GEMM (R9-value-verified, R20-safety-verified) --------------
// C[m][coloffz+n] = sum_k A[m][k]*B[k][n] + bias[n]; z-fused over 3 weights.
__global__ __launch_bounds__(256) void gemm_nt_k(const __bf16* __restrict__ A,
                                                 const __bf16* __restrict__ B,
                                                 const float* __restrict__ bias,
                                                 __bf16* __restrict__ C,
                                                 int M, int N, int K, int ldc) {
  const int z = blockIdx.z;
  const __bf16* Bz = B + (size_t)z * 1048576;
  const float* biasz = bias + z * 1024;
  const int coloffz = z * 1024;
  const int tm = blockIdx.x * 128, tn = blockIdx.y * 128;
  const int tid = threadIdx.x;
  const int w = tid >> 6, l = tid & 63;
  const int l15 = l & 15, l4 = l >> 4;
  const int wm = (w >> 1) * 64, wn = (w & 1) * 64;
  __shared__ __bf16 As[128][72];
  __shared__ __bf16 Bs[128][72];
  f32x4 acc[4][4] = {};
  for (int kt = 0; kt < K; kt += 64) {
    __syncthreads();
#pragma unroll
    for (int i = 0; i < 4; ++i) {
      int c = tid + i * 256;
      int r = c >> 3, s = (c & 7) * 8;
      *(bf16x8*)(&As[r][s]) = *(const bf16x8*)(A + (size_t)(tm + r) * K + kt + s);
    }
#pragma unroll
    for (int i = 0; i < 4; ++i) {
      int c = tid + i * 256;
      int kr = c >> 4, nc = (c & 15) * 8;
      bf16x8 bv = *(const bf16x8*)(Bz + (size_t)(kt + kr) * N + tn + nc);
#pragma unroll
      for (int j = 0; j < 8; ++j) Bs[nc + j][kr] = bv[j];
    }
    __syncthreads();
#pragma unroll
    for (int kk = 0; kk < 2; ++kk) {
      bf16x8 af[4], bfr[4];
#pragma unroll
      for (int m = 0; m < 4; ++m)
        af[m] = *(const bf16x8*)(&As[wm + m * 16 + l15][kk * 32 + l4 * 8]);
#pragma unroll
      for (int n = 0; n < 4; ++n)
        bfr[n] = *(const bf16x8*)(&Bs[wn + n * 16 + l15][kk * 32 + l4 * 8]);
#pragma unroll
      for (int m = 0; m < 4; ++m)
#pragma unroll
        for (int n = 0; n < 4; ++n)
          acc[m][n] = mfma16(af[m], bfr[n], acc[m][n]);
    }
  }
#pragma unroll
  for (int m = 0; m < 4; ++m)
#pragma unroll
    for (int n = 0; n < 4; ++n) {
      int row = tm + wm + m * 16 + l4 * 4;
      int col = tn + wn + n * 16 + l15;
      float bb = biasz[col];
#pragma unroll
      for (int r = 0; r < 4; ++r)
        C[(size_t)(row + r) * ldc + coloffz + col] = (__bf16)(acc[m][n][r] + bb);
    }
}

// Output-projection variant: dtype-branched scalar store to d_out.
__global__ __launch_bounds__(256) void gemm_nt_out_k(const __bf16* __restrict__ A,
                                                     const __bf16* __restrict__ B,
                                                     const float* __restrict__ bias,
                                                     void* __restrict__ out,
                                                     int M, int N, int K,
                                                     const int* __restrict__ flag) {
  const int tm = blockIdx.x * 128, tn = blockIdx.y * 128;
  const int tid = threadIdx.x;
  const int w = tid >> 6, l = tid & 63;
  const int l15 = l & 15, l4 = l >> 4;
  const int wm = (w >> 1) * 64, wn = (w & 1) * 64;
  __shared__ __bf16 As[128][72];
  __shared__ __bf16 Bs[128][72];
  f32x4 acc[4][4] = {};
  for (int kt = 0; kt < K; kt += 64) {
    __syncthreads();
#pragma unroll
    for (int i = 0; i < 4; ++i) {
      int c = tid + i * 256;
      int r = c >> 3, s = (c & 7) * 8;
      *(bf16x8*)(&As[r][s]) = *(const bf16x8*)(A + (size_t)(tm + r) * K + kt + s);
    }
#pragma unroll
    for (int i = 0; i < 4; ++i) {
      int c = tid + i * 256;
      int kr = c >> 4, nc = (c & 15) * 8;
      bf16x8 bv = *(const bf16x8*)(B + (size_t)(kt + kr) * N + tn + nc);
#pragma unroll
      for (int j = 0; j < 8; ++j) Bs[nc + j][kr] = bv[j];
    }
    __syncthreads();
#pragma unroll
    for (int kk = 0; kk < 2; ++kk) {
      bf16x8 af[4], bfr[4];
#pragma unroll
      for (int m = 0; m < 4; ++m)
        af[m] = *(const bf16x8*)(&As[wm + m * 16 + l15][kk * 32 + l4 * 8]);
#pragma unroll
      for (int n = 0; n < 4; ++n)
        bfr[n] = *(const bf16x8*)(&Bs[wn + n * 16 + l15][kk * 32 + l4 * 8]);
#pragma unroll
      for (int m = 0; m < 4; ++m)
#pragma unroll
        for (int n = 0; n < 4; ++n)
          acc[m][n] = mfma16(af[m], bfr[n], acc[m][n]);
    }
  }
  int use16 = *flag;
#pragma unroll
  for (int m = 0; m < 4; ++m)
#pragma unroll
    for (int n = 0; n < 4; ++n) {
      int row = tm + wm + m * 16 + l4 * 4;
      int col = tn + wn + n * 16 + l15;
      float bb = bias[col];
#pragma unroll
      for (int r = 0; r < 4; ++r) {
        float v = acc[m][n][r] + bb;
        size_t idx = (size_t)(row + r) * N + col;
        if (use16) ((__bf16*)out)[idx] = (__bf16)v;
        else       ((float*)out)[idx] = v;
      }
    }
}

// ---------------- V transpose (proven) ----------------
__global__ __launch_bounds__(256) void vt_k(const __bf16* __restrict__ QKVb,
                                            __bf16* __restrict__ Vt) {
  __shared__ __bf16 t[64][72];
  const int h = blockIdx.x, k0 = blockIdx.y * 64;
  const int tid = threadIdx.x;
  const int r = tid >> 2, dc = (tid & 3) * 16;
  const __bf16* src = QKVb + (size_t)(k0 + r) * 3072 + 2048 + h * 64 + dc;
  *(bf16x8*)(&t[r][dc]) = *(const bf16x8*)(src);
  *(bf16x8*)(&t[r][dc + 8]) = *(const bf16x8*)(src + 8);
  __syncthreads();
  const int dr = tid >> 2, kc = (tid & 3) * 16;
  __bf16* dst = Vt + ((size_t)(h * 64 + dr)) * 1024 + k0 + kc;
  bf16x8 o0, o1;
#pragma unroll
  for (int j = 0; j < 8; ++j) { o0[j] = t[kc + j][dr]; o1[j] = t[kc + 8 + j][dr]; }
  *(bf16x8*)dst = o0;
  *(bf16x8*)(dst + 8) = o1;
}

// ---------------- attention v9 (R18-proven, 447 us) ----------------
__global__ __launch_bounds__(256) void attn_v9_k(const __bf16* __restrict__ QKV,
                                                 const __bf16* __restrict__ Vt,
                                                 const float* __restrict__ amask,
                                                 const __bf16* __restrict__ rel16,
                                                 const float* __restrict__ Mg,
                                                 const float* __restrict__ zg,
                                                 const float* __restrict__ ga,
                                                 __bf16* __restrict__ comb) {
  const int q0 = blockIdx.x * 4, h = blockIdx.y;
  const int tid = threadIdx.x;
  __shared__ float sc[4][1024];
  __shared__ __bf16 qsb[4][64];
  __shared__ f32x4v red4[256];
  __shared__ float ov[4][4][64];
  __shared__ float sq_s[4][64];

  {
    int qq = tid >> 6, d = tid & 63;
    qsb[qq][d] = QKV[(size_t)(q0 + qq) * 3072 + h * 64 + d];
  }
  __syncthreads();

#pragma unroll 1
  for (int jj = 0; jj < 4; ++jj) {
    int k = tid + jj * 256;
    const __bf16* kp = QKV + (size_t)k * 3072 + 1024 + h * 64;
    bf16x8 kv[8];
#pragma unroll
    for (int c = 0; c < 8; ++c) kv[c] = *(const bf16x8*)(kp + c * 8);
    float mk = amask[k] * (-1e9f);
#pragma unroll 1
    for (int qq = 0; qq < 4; ++qq) {
      const __bf16* rp = rel16 + (size_t)(q0 + qq - k + 1024) * 64;
      const __bf16* qp = &qsb[qq][0];
      float p[4] = {0.f, 0.f, 0.f, 0.f};
#pragma unroll
      for (int c = 0; c < 8; ++c) {
        bf16x8 rv = *(const bf16x8*)(rp + c * 8);
        bf16x8 qv = *(const bf16x8*)(qp + c * 8);
#pragma unroll
        for (int e = 0; e < 8; ++e)
          p[c & 3] += ((float)qv[e] + (float)rv[e]) * (float)kv[c][e];
      }
      float s = (p[0] + p[1]) + (p[2] + p[3]);
      sc[qq][k] = s * 0.125f + mk;
    }
  }
  __syncthreads();

  f32x4v mx;
  mx[0] = mx[1] = mx[2] = mx[3] = -3.0e38f;
  for (int k = tid; k < 1024; k += 256) {
    mx[0] = fmaxf(mx[0], sc[0][k]);
    mx[1] = fmaxf(mx[1], sc[1][k]);
    mx[2] = fmaxf(mx[2], sc[2][k]);
    mx[3] = fmaxf(mx[3], sc[3][k]);
  }
  red4[tid] = mx;
  __syncthreads();
  for (int s = 128; s > 0; s >>= 1) {
    if (tid < s) {
      f32x4v a = red4[tid], b = red4[tid + s];
      a[0] = fmaxf(a[0], b[0]); a[1] = fmaxf(a[1], b[1]);
      a[2] = fmaxf(a[2], b[2]); a[3] = fmaxf(a[3], b[3]);
      red4[tid] = a;
    }
    __syncthreads();
  }
  f32x4v mrow = red4[0];
  __syncthreads();

  f32x4v lp = {0.f, 0.f, 0.f, 0.f};
  for (int k = tid; k < 1024; k += 256) {
    float e0 = __expf(sc[0][k] - mrow[0]); sc[0][k] = e0; lp[0] += e0;
    float e1 = __expf(sc[1][k] - mrow[1]); sc[1][k] = e1; lp[1] += e1;
    float e2 = __expf(sc[2][k] - mrow[2]); sc[2][k] = e2; lp[2] += e2;
    float e3 = __expf(sc[3][k] - mrow[3]); sc[3][k] = e3; lp[3] += e3;
  }
  red4[tid] = lp;
  __syncthreads();
  for (int s = 128; s > 0; s >>= 1) {
    if (tid < s) {
      f32x4v a = red4[tid], b = red4[tid + s];
      a[0] += b[0]; a[1] += b[1]; a[2] += b[2]; a[3] += b[3];
      red4[tid] = a;
    }
    __syncthreads();
  }
  f32x4v lsum = red4[0];

  const int d = tid & 63, w4 = tid >> 6;
  float o0 = 0.f, o1 = 0.f, o2 = 0.f, o3 = 0.f;
  const __bf16* vrow = Vt + ((size_t)(h * 64 + d)) * 1024 + w4 * 256;
#pragma unroll 4
  for (int c = 0; c < 32; ++c) {
    bf16x8 vv = *(const bf16x8*)(vrow + c * 8);
    int k0 = w4 * 256 + c * 8;
#pragma unroll
    for (int e = 0; e < 8; ++e) {
      float v = (float)vv[e];
      o0 += sc[0][k0 + e] * v;
      o1 += sc[1][k0 + e] * v;
      o2 += sc[2][k0 + e] * v;
      o3 += sc[3][k0 + e] * v;
    }
  }
  ov[w4][0][d] = o0; ov[w4][1][d] = o1; ov[w4][2][d] = o2; ov[w4][3][d] = o3;
  __syncthreads();

  {
    int qq = tid >> 6, dd = tid & 63;
    float x = (float)qsb[qq][dd];
    sq_s[qq][dd] = x > 0.f ? x + 1.f : __expf(x);
  }
  __syncthreads();

  {
    int qq = tid >> 6, d2 = tid & 63;
    float local = (ov[0][qq][d2] + ov[1][qq][d2] + ov[2][qq][d2] + ov[3][qq][d2]) /
                  lsum[qq];
    float num = 0.f, den = 1e-6f;
#pragma unroll
    for (int dd = 0; dd < 64; ++dd) {
      float sqv = sq_s[qq][dd];
      num += sqv * Mg[(size_t)h * 4096 + dd * 64 + d2];
      den += sqv * zg[h * 64 + dd];
    }
    float gate = 1.f / (1.f + __expf(-ga[0]));
    float cv = gate * local + (1.f - gate) * num / den;
    comb[(size_t)(q0 + qq) * 1024 + h * 64 + d2] = (__bf16)cv;
  }
}

// ---------------- launcher ----------------
extern "C" void kernel_launch(void* const* d_in, const int* in_sizes, int n_in,
                              void* d_out, int out_size, void* d_ws, size_t ws_size,
                              hipStream_t stream) {
  const int expect[14] = {4194304, 4096, 1048576, 1024, 1048576, 1024, 1048576,
                          1024, 1048576, 1024, 131136, 65536, 1024, 1};
  if (n_in != 14) return;
  for (int i = 0; i < 14; ++i)
    if (in_sizes[i] != expect[i]) return;

  char* ws = (char*)d_ws;
  int*    flag  = (int*)ws;                      // 4B
  float*  am32  = (float*)(ws + 1024);           // [4096]
  float*  b32   = (float*)(ws + 17408);          // bq|bk|bv|bo  [4][1024]
  float*  zg32  = (float*)(ws + 33792);          // [1024]
  float*  ga32  = (float*)(ws + 37888);          // [1]
  float*  Mg32  = (float*)(ws + 38912);          // [65536]
  __bf16* rel16 = (__bf16*)(ws + 301056);        // [131136]
  __bf16* hs16  = (__bf16*)(ws + 565248);        // [4096][1024]
  __bf16* W16   = (__bf16*)(ws + 8953856);       // 4x [1024][1024] (q,k,v,o)
  __bf16* qkv_b = (__bf16*)(ws + 17342464);      // [1024][3072]
  __bf16* comb  = (__bf16*)(ws + 23633920);      // [4096][1024]  ends 32022528
  __bf16* Vt    = (__bf16*)(ws + 32022528);      // [16][64][1024] ends 34119680

  detect_k<<<1, 256, 0, stream>>>((const uint32_t*)d_in[0], flag);

  cvt_to_bf16_k<<<16384, 256, 0, stream>>>(d_in[0], hs16, 4194304, flag);
  cvt_to_f32_k<<<16, 256, 0, stream>>>(d_in[1], am32, 4096, flag);
  const int widx[4] = {2, 4, 6, 8};
  for (int j = 0; j < 4; ++j) {
    cvt_to_bf16_k<<<4096, 256, 0, stream>>>(d_in[widx[j]], W16 + (size_t)j * 1048576,
                                            1048576, flag);
    cvt_to_f32_k<<<4, 256, 0, stream>>>(d_in[widx[j] + 1], b32 + j * 1024, 1024, flag);
  }
  cvt_to_bf16_k<<<513, 256, 0, stream>>>(d_in[10], rel16, 131136, flag);
  cvt_to_f32_k<<<256, 256, 0, stream>>>(d_in[11], Mg32, 65536, flag);
  cvt_to_f32_k<<<4, 256, 0, stream>>>(d_in[12], zg32, 1024, flag);
  cvt_to_f32_k<<<1, 256, 0, stream>>>(d_in[13], ga32, 1, flag);

  for (int b = 0; b < 4; ++b) {
    // MFMA QKV projection (ws inputs only): z selects Wq/Wk/Wv
    gemm_nt_k<<<dim3(8, 8, 3), 256, 0, stream>>>(
        hs16 + (size_t)b * 1048576, W16, b32, qkv_b, 1024, 1024, 1024, 3072);
    vt_k<<<dim3(16, 16), 256, 0, stream>>>(qkv_b, Vt);
    attn_v9_k<<<dim3(256, 16), 256, 0, stream>>>(
        qkv_b, Vt, am32 + b * 1024, rel16, Mg32, zg32, ga32,
        comb + (size_t)b * 1048576);
  }

  // MFMA output projection (ws inputs; dtype-branched store to d_out)
  gemm_nt_out_k<<<dim3(32, 8), 256, 0, stream>>>(
      comb, W16 + 3 * 1048576, b32 + 3072, d_out, 4096, 1024, 1024, flag);
}

// Round 22
// 528.310 us; speedup vs baseline: 5.1901x; 3.5842x over previous
//
#include <hip/hip_runtime.h>
#include <cstdint>
#include <cstddef>

typedef __bf16 bf16x8 __attribute__((ext_vector_type(8)));
typedef float f32x4 __attribute__((ext_vector_type(4)));

static __device__ __forceinline__ f32x4 mfma16(bf16x8 a, bf16x8 b, f32x4 c) {
  return __builtin_amdgcn_mfma_f32_16x16x32_bf16(a, b, c, 0, 0, 0);
}

// LAW (R19/R20 proven): compute kernels must NEVER vector-load from d_in —
// d_in is only touched by scalar converter kernels; all bf16x8 loads hit ws.

// ---------------- input dtype sniffing (proven) ----------------
__global__ __launch_bounds__(256) void detect_k(const uint32_t* __restrict__ hs,
                                                int* __restrict__ flag) {
  __shared__ int cnt;
  if (threadIdx.x == 0) cnt = 0;
  __syncthreads();
  uint32_t w = hs[threadIdx.x];
  int b = (w >> 8) & 0x7F;
  if (b >= 0x3C && b <= 0x40) atomicAdd(&cnt, 1);
  __syncthreads();
  if (threadIdx.x == 0) *flag = (cnt >= 128) ? 1 : 0;
}

// ---------------- dtype-adaptive converters (proven; SCALAR d_in reads) ----------
__global__ __launch_bounds__(256) void cvt_to_bf16_k(const void* __restrict__ src,
                                                     __bf16* __restrict__ dst, int n,
                                                     const int* __restrict__ flag) {
  int i = blockIdx.x * 256 + threadIdx.x;
  if (i >= n) return;
  float v = (*flag) ? (float)((const __bf16*)src)[i] : ((const float*)src)[i];
  dst[i] = (__bf16)v;
}

__global__ __launch_bounds__(256) void cvt_to_f32_k(const void* __restrict__ src,
                                                    float* __restrict__ dst, int n,
                                                    const int* __restrict__ flag) {
  int i = blockIdx.x * 256 + threadIdx.x;
  if (i >= n) return;
  dst[i] = (*flag) ? (float)((const __bf16*)src)[i] : ((const float*)src)[i];
}

// ---------------- MFMA GEMM (R21-proven) ----------------
__global__ __launch_bounds__(256) void gemm_nt_k(const __bf16* __restrict__ A,
                                                 const __bf16* __restrict__ B,
                                                 const float* __restrict__ bias,
                                                 __bf16* __restrict__ C,
                                                 int M, int N, int K, int ldc) {
  const int z = blockIdx.z;
  const __bf16* Bz = B + (size_t)z * 1048576;
  const float* biasz = bias + z * 1024;
  const int coloffz = z * 1024;
  const int tm = blockIdx.x * 128, tn = blockIdx.y * 128;
  const int tid = threadIdx.x;
  const int w = tid >> 6, l = tid & 63;
  const int l15 = l & 15, l4 = l >> 4;
  const int wm = (w >> 1) * 64, wn = (w & 1) * 64;
  __shared__ __bf16 As[128][72];
  __shared__ __bf16 Bs[128][72];
  f32x4 acc[4][4] = {};
  for (int kt = 0; kt < K; kt += 64) {
    __syncthreads();
#pragma unroll
    for (int i = 0; i < 4; ++i) {
      int c = tid + i * 256;
      int r = c >> 3, s = (c & 7) * 8;
      *(bf16x8*)(&As[r][s]) = *(const bf16x8*)(A + (size_t)(tm + r) * K + kt + s);
    }
#pragma unroll
    for (int i = 0; i < 4; ++i) {
      int c = tid + i * 256;
      int kr = c >> 4, nc = (c & 15) * 8;
      bf16x8 bv = *(const bf16x8*)(Bz + (size_t)(kt + kr) * N + tn + nc);
#pragma unroll
      for (int j = 0; j < 8; ++j) Bs[nc + j][kr] = bv[j];
    }
    __syncthreads();
#pragma unroll
    for (int kk = 0; kk < 2; ++kk) {
      bf16x8 af[4], bfr[4];
#pragma unroll
      for (int m = 0; m < 4; ++m)
        af[m] = *(const bf16x8*)(&As[wm + m * 16 + l15][kk * 32 + l4 * 8]);
#pragma unroll
      for (int n = 0; n < 4; ++n)
        bfr[n] = *(const bf16x8*)(&Bs[wn + n * 16 + l15][kk * 32 + l4 * 8]);
#pragma unroll
      for (int m = 0; m < 4; ++m)
#pragma unroll
        for (int n = 0; n < 4; ++n)
          acc[m][n] = mfma16(af[m], bfr[n], acc[m][n]);
    }
  }
#pragma unroll
  for (int m = 0; m < 4; ++m)
#pragma unroll
    for (int n = 0; n < 4; ++n) {
      int row = tm + wm + m * 16 + l4 * 4;
      int col = tn + wn + n * 16 + l15;
      float bb = biasz[col];
#pragma unroll
      for (int r = 0; r < 4; ++r)
        C[(size_t)(row + r) * ldc + coloffz + col] = (__bf16)(acc[m][n][r] + bb);
    }
}

__global__ __launch_bounds__(256) void gemm_nt_out_k(const __bf16* __restrict__ A,
                                                     const __bf16* __restrict__ B,
                                                     const float* __restrict__ bias,
                                                     void* __restrict__ out,
                                                     int M, int N, int K,
                                                     const int* __restrict__ flag) {
  const int tm = blockIdx.x * 128, tn = blockIdx.y * 128;
  const int tid = threadIdx.x;
  const int w = tid >> 6, l = tid & 63;
  const int l15 = l & 15, l4 = l >> 4;
  const int wm = (w >> 1) * 64, wn = (w & 1) * 64;
  __shared__ __bf16 As[128][72];
  __shared__ __bf16 Bs[128][72];
  f32x4 acc[4][4] = {};
  for (int kt = 0; kt < K; kt += 64) {
    __syncthreads();
#pragma unroll
    for (int i = 0; i < 4; ++i) {
      int c = tid + i * 256;
      int r = c >> 3, s = (c & 7) * 8;
      *(bf16x8*)(&As[r][s]) = *(const bf16x8*)(A + (size_t)(tm + r) * K + kt + s);
    }
#pragma unroll
    for (int i = 0; i < 4; ++i) {
      int c = tid + i * 256;
      int kr = c >> 4, nc = (c & 15) * 8;
      bf16x8 bv = *(const bf16x8*)(B + (size_t)(kt + kr) * N + tn + nc);
#pragma unroll
      for (int j = 0; j < 8; ++j) Bs[nc + j][kr] = bv[j];
    }
    __syncthreads();
#pragma unroll
    for (int kk = 0; kk < 2; ++kk) {
      bf16x8 af[4], bfr[4];
#pragma unroll
      for (int m = 0; m < 4; ++m)
        af[m] = *(const bf16x8*)(&As[wm + m * 16 + l15][kk * 32 + l4 * 8]);
#pragma unroll
      for (int n = 0; n < 4; ++n)
        bfr[n] = *(const bf16x8*)(&Bs[wn + n * 16 + l15][kk * 32 + l4 * 8]);
#pragma unroll
      for (int m = 0; m < 4; ++m)
#pragma unroll
        for (int n = 0; n < 4; ++n)
          acc[m][n] = mfma16(af[m], bfr[n], acc[m][n]);
    }
  }
  int use16 = *flag;
#pragma unroll
  for (int m = 0; m < 4; ++m)
#pragma unroll
    for (int n = 0; n < 4; ++n) {
      int row = tm + wm + m * 16 + l4 * 4;
      int col = tn + wn + n * 16 + l15;
      float bb = bias[col];
#pragma unroll
      for (int r = 0; r < 4; ++r) {
        float v = acc[m][n][r] + bb;
        size_t idx = (size_t)(row + r) * N + col;
        if (use16) ((__bf16*)out)[idx] = (__bf16)v;
        else       ((float*)out)[idx] = v;
      }
    }
}

// ---------------- MFMA fused attention (R5/R6 design, ws-only inputs) ----------------
// One batch per launch: QKVb [1024][3072] bf16 in ws. grid (16 q-tiles, 16 heads).
__global__ __launch_bounds__(256) void attn_fused_k(const __bf16* __restrict__ QKVb,
                                                    const float* __restrict__ amask,
                                                    const __bf16* __restrict__ rel16,
                                                    const __bf16* __restrict__ Mg16,
                                                    const float* __restrict__ zg32,
                                                    const float* __restrict__ ga32,
                                                    __bf16* __restrict__ comb) {
  const int qt = blockIdx.x, h = blockIdx.y;
  const int tid = threadIdx.x;
  const int w = tid >> 6, l = tid & 63;
  const int l15 = l & 15, l4 = l >> 4;
  const int q0 = qt * 64;

  __shared__ __bf16 Kt[64][72];
  __shared__ __bf16 VtT[64][72];
  __shared__ __bf16 Pl[4][16 * 72];
  __shared__ float RKb[128 * 65];
  __shared__ float maskv[64];
  __shared__ float denv[64];

  bf16x8 qf[2];
#pragma unroll
  for (int kk = 0; kk < 2; ++kk)
    qf[kk] = *(const bf16x8*)(QKVb + (size_t)(q0 + w * 16 + l15) * 3072 + h * 64 +
                              l4 * 8 + kk * 32);

  f32x4 accO[4] = {};
  float mrun[4], lrun[4];
#pragma unroll
  for (int r = 0; r < 4; ++r) { mrun[r] = -3.0e38f; lrun[r] = 0.f; }

  for (int kt = 0; kt < 16; ++kt) {
    const int k0 = kt * 64;
    __syncthreads();
#pragma unroll
    for (int i = 0; i < 2; ++i) {
      int c = tid + i * 256;
      int kr = c >> 3, s = (c & 7) * 8;
      const __bf16* src = QKVb + (size_t)(k0 + kr) * 3072 + h * 64;
      *(bf16x8*)(&Kt[kr][s]) = *(const bf16x8*)(src + 1024 + s);
      bf16x8 vv = *(const bf16x8*)(src + 2048 + s);
#pragma unroll
      for (int j = 0; j < 8; ++j) VtT[s + j][kr] = vv[j];
    }
    if (tid < 64) maskv[tid] = amask[k0 + tid];
    __syncthreads();

    // RK[j][k] = sum_d rel16[jb+j][d] * K[k][d]
    const int jb = q0 - k0 - 63 + 1024;
#pragma unroll
    for (int ms = 0; ms < 2; ++ms) {
      f32x4 rk[4] = {};
#pragma unroll
      for (int kk = 0; kk < 2; ++kk) {
        bf16x8 ea = *(const bf16x8*)(rel16 + (size_t)(jb + w * 32 + ms * 16 + l15) * 64 +
                                     l4 * 8 + kk * 32);
#pragma unroll
        for (int nb = 0; nb < 4; ++nb) {
          bf16x8 kb = *(const bf16x8*)(&Kt[nb * 16 + l15][l4 * 8 + kk * 32]);
          rk[nb] = mfma16(ea, kb, rk[nb]);
        }
      }
#pragma unroll
      for (int nb = 0; nb < 4; ++nb)
#pragma unroll
        for (int r = 0; r < 4; ++r)
          RKb[(w * 32 + ms * 16 + l4 * 4 + r) * 65 + nb * 16 + l15] = rk[nb][r];
    }
    __syncthreads();

    // content scores
    f32x4 sacc[4] = {};
#pragma unroll
    for (int kk = 0; kk < 2; ++kk)
#pragma unroll
      for (int nb = 0; nb < 4; ++nb) {
        bf16x8 kb = *(const bf16x8*)(&Kt[nb * 16 + l15][l4 * 8 + kk * 32]);
        sacc[nb] = mfma16(qf[kk], kb, sacc[nb]);
      }

    // scores + online softmax
    float p[4][4];
    float tmax[4];
#pragma unroll
    for (int r = 0; r < 4; ++r) tmax[r] = -3.0e38f;
#pragma unroll
    for (int nb = 0; nb < 4; ++nb) {
      int kloc = nb * 16 + l15;
      float mk = maskv[kloc] * (-1e9f);
#pragma unroll
      for (int r = 0; r < 4; ++r) {
        int jl = (w * 16 + l4 * 4 + r) - kloc + 63;
        float s = (sacc[nb][r] + RKb[jl * 65 + kloc]) * 0.125f + mk;
        p[nb][r] = s;
        tmax[r] = fmaxf(tmax[r], s);
      }
    }
#pragma unroll
    for (int x = 1; x < 16; x <<= 1)
#pragma unroll
      for (int r = 0; r < 4; ++r) tmax[r] = fmaxf(tmax[r], __shfl_xor(tmax[r], x, 64));
    float al[4];
#pragma unroll
    for (int r = 0; r < 4; ++r) {
      float mn = fmaxf(mrun[r], tmax[r]);
      al[r] = __expf(mrun[r] - mn);
      mrun[r] = mn;
    }
    float rs[4] = {0.f, 0.f, 0.f, 0.f};
#pragma unroll
    for (int nb = 0; nb < 4; ++nb)
#pragma unroll
      for (int r = 0; r < 4; ++r) {
        p[nb][r] = __expf(p[nb][r] - mrun[r]);
        rs[r] += p[nb][r];
      }
#pragma unroll
    for (int x = 1; x < 16; x <<= 1)
#pragma unroll
      for (int r = 0; r < 4; ++r) rs[r] += __shfl_xor(rs[r], x, 64);
#pragma unroll
    for (int r = 0; r < 4; ++r) lrun[r] = lrun[r] * al[r] + rs[r];
#pragma unroll
    for (int nb = 0; nb < 4; ++nb)
#pragma unroll
      for (int r = 0; r < 4; ++r) accO[nb][r] *= al[r];

    // P -> per-wave LDS transpose
#pragma unroll
    for (int nb = 0; nb < 4; ++nb)
#pragma unroll
      for (int r = 0; r < 4; ++r)
        Pl[w][(l4 * 4 + r) * 72 + nb * 16 + l15] = (__bf16)p[nb][r];
    __syncthreads();  // ordering for cross-lane Pl write->read (R6 fix)

    // PV
#pragma unroll
    for (int kk = 0; kk < 2; ++kk) {
      bf16x8 pa = *(const bf16x8*)(&Pl[w][l15 * 72 + kk * 32 + l4 * 8]);
#pragma unroll
      for (int nb = 0; nb < 4; ++nb) {
        bf16x8 vb = *(const bf16x8*)(&VtT[nb * 16 + l15][kk * 32 + l4 * 8]);
        accO[nb] = mfma16(pa, vb, accO[nb]);
      }
    }
  }

#pragma unroll
  for (int nb = 0; nb < 4; ++nb)
#pragma unroll
    for (int r = 0; r < 4; ++r) accO[nb][r] /= lrun[r];

  // ---- epilogue: global branch + gate-combine (overlays RKb) ----
  __syncthreads();
  __bf16* sqb = (__bf16*)RKb;
  __bf16* Mtb = ((__bf16*)RKb) + 64 * 72;
#pragma unroll
  for (int i = 0; i < 2; ++i) {
    int c = tid + i * 256;
    int qr = c >> 3, s = (c & 7) * 8;
    bf16x8 qv = *(const bf16x8*)(QKVb + (size_t)(q0 + qr) * 3072 + h * 64 + s);
#pragma unroll
    for (int j = 0; j < 8; ++j) {
      float x = (float)qv[j];
      sqb[qr * 72 + s + j] = (__bf16)(x > 0.f ? x + 1.f : __expf(x));
    }
    bf16x8 mv = *(const bf16x8*)(Mg16 + (size_t)h * 4096 + qr * 64 + s);
#pragma unroll
    for (int j = 0; j < 8; ++j) Mtb[(s + j) * 72 + qr] = mv[j];
  }
  __syncthreads();
  if (tid < 64) {
    float sden = 0.f;
    const float* zp = zg32 + h * 64;
#pragma unroll
    for (int d = 0; d < 64; ++d) sden += (float)sqb[tid * 72 + d] * zp[d];
    denv[tid] = sden + 1e-6f;
  }
  __syncthreads();
  float gate = 1.f / (1.f + __expf(-ga32[0]));
  f32x4 nacc[4] = {};
#pragma unroll
  for (int kk = 0; kk < 2; ++kk) {
    bf16x8 sa = *(const bf16x8*)(sqb + (w * 16 + l15) * 72 + kk * 32 + l4 * 8);
#pragma unroll
    for (int nb = 0; nb < 4; ++nb) {
      bf16x8 mb = *(const bf16x8*)(Mtb + (nb * 16 + l15) * 72 + kk * 32 + l4 * 8);
      nacc[nb] = mfma16(sa, mb, nacc[nb]);
    }
  }
#pragma unroll
  for (int nb = 0; nb < 4; ++nb)
#pragma unroll
    for (int r = 0; r < 4; ++r) {
      int qrel = w * 16 + l4 * 4 + r;
      float gl = nacc[nb][r] / denv[qrel];
      float cv = gate * accO[nb][r] + (1.f - gate) * gl;
      comb[(size_t)(q0 + qrel) * 1024 + h * 64 + nb * 16 + l15] = (__bf16)cv;
    }
}

// ---------------- launcher ----------------
extern "C" void kernel_launch(void* const* d_in, const int* in_sizes, int n_in,
                              void* d_out, int out_size, void* d_ws, size_t ws_size,
                              hipStream_t stream) {
  const int expect[14] = {4194304, 4096, 1048576, 1024, 1048576, 1024, 1048576,
                          1024, 1048576, 1024, 131136, 65536, 1024, 1};
  if (n_in != 14) return;
  for (int i = 0; i < 14; ++i)
    if (in_sizes[i] != expect[i]) return;

  char* ws = (char*)d_ws;
  int*    flag  = (int*)ws;                      // 4B
  float*  am32  = (float*)(ws + 1024);           // [4096]
  float*  b32   = (float*)(ws + 17408);          // bq|bk|bv|bo  [4][1024]
  float*  zg32  = (float*)(ws + 33792);          // [1024]
  float*  ga32  = (float*)(ws + 37888);          // [1]
  __bf16* Mg16  = (__bf16*)(ws + 38912);         // [65536] bf16 (131072 B)
  __bf16* rel16 = (__bf16*)(ws + 301056);        // [131136]
  __bf16* hs16  = (__bf16*)(ws + 565248);        // [4096][1024]
  __bf16* W16   = (__bf16*)(ws + 8953856);       // 4x [1024][1024] (q,k,v,o)
  __bf16* qkv_b = (__bf16*)(ws + 17342464);      // [1024][3072]
  __bf16* comb  = (__bf16*)(ws + 23633920);      // [4096][1024]  ends 32022528

  detect_k<<<1, 256, 0, stream>>>((const uint32_t*)d_in[0], flag);

  cvt_to_bf16_k<<<16384, 256, 0, stream>>>(d_in[0], hs16, 4194304, flag);
  cvt_to_f32_k<<<16, 256, 0, stream>>>(d_in[1], am32, 4096, flag);
  const int widx[4] = {2, 4, 6, 8};
  for (int j = 0; j < 4; ++j) {
    cvt_to_bf16_k<<<4096, 256, 0, stream>>>(d_in[widx[j]], W16 + (size_t)j * 1048576,
                                            1048576, flag);
    cvt_to_f32_k<<<4, 256, 0, stream>>>(d_in[widx[j] + 1], b32 + j * 1024, 1024, flag);
  }
  cvt_to_bf16_k<<<513, 256, 0, stream>>>(d_in[10], rel16, 131136, flag);
  cvt_to_bf16_k<<<256, 256, 0, stream>>>(d_in[11], Mg16, 65536, flag);
  cvt_to_f32_k<<<4, 256, 0, stream>>>(d_in[12], zg32, 1024, flag);
  cvt_to_f32_k<<<1, 256, 0, stream>>>(d_in[13], ga32, 1, flag);

  for (int b = 0; b < 4; ++b) {
    gemm_nt_k<<<dim3(8, 8, 3), 256, 0, stream>>>(
        hs16 + (size_t)b * 1048576, W16, b32, qkv_b, 1024, 1024, 1024, 3072);
    attn_fused_k<<<dim3(16, 16), 256, 0, stream>>>(
        qkv_b, am32 + b * 1024, rel16, Mg16, zg32, ga32,
        comb + (size_t)b * 1048576);
  }

  gemm_nt_out_k<<<dim3(32, 8), 256, 0, stream>>>(
      comb, W16 + 3 * 1048576, b32 + 3072, d_out, 4096, 1024, 1024, flag);
}

// Round 23
// 430.369 us; speedup vs baseline: 6.3713x; 1.2276x over previous
//
#include <hip/hip_runtime.h>
#include <cstdint>
#include <cstddef>

typedef __bf16 bf16x8 __attribute__((ext_vector_type(8)));
typedef float f32x4 __attribute__((ext_vector_type(4)));

static __device__ __forceinline__ f32x4 mfma16(bf16x8 a, bf16x8 b, f32x4 c) {
  return __builtin_amdgcn_mfma_f32_16x16x32_bf16(a, b, c, 0, 0, 0);
}

// LAW (R19/R20 proven): compute kernels must NEVER vector-load from d_in —
// d_in is only touched by scalar converter kernels; all bf16x8 loads hit ws.

// ---------------- input dtype sniffing (proven) ----------------
__global__ __launch_bounds__(256) void detect_k(const uint32_t* __restrict__ hs,
                                                int* __restrict__ flag) {
  __shared__ int cnt;
  if (threadIdx.x == 0) cnt = 0;
  __syncthreads();
  uint32_t w = hs[threadIdx.x];
  int b = (w >> 8) & 0x7F;
  if (b >= 0x3C && b <= 0x40) atomicAdd(&cnt, 1);
  __syncthreads();
  if (threadIdx.x == 0) *flag = (cnt >= 128) ? 1 : 0;
}

// ---------------- dtype-adaptive converters (proven; SCALAR d_in reads) ----------
__global__ __launch_bounds__(256) void cvt_to_bf16_k(const void* __restrict__ src,
                                                     __bf16* __restrict__ dst, int n,
                                                     const int* __restrict__ flag) {
  int i = blockIdx.x * 256 + threadIdx.x;
  if (i >= n) return;
  float v = (*flag) ? (float)((const __bf16*)src)[i] : ((const float*)src)[i];
  dst[i] = (__bf16)v;
}

__global__ __launch_bounds__(256) void cvt_to_f32_k(const void* __restrict__ src,
                                                    float* __restrict__ dst, int n,
                                                    const int* __restrict__ flag) {
  int i = blockIdx.x * 256 + threadIdx.x;
  if (i >= n) return;
  dst[i] = (*flag) ? (float)((const __bf16*)src)[i] : ((const float*)src)[i];
}

// ---------------- MFMA GEMM (R21-proven) ----------------
__global__ __launch_bounds__(256) void gemm_nt_k(const __bf16* __restrict__ A,
                                                 const __bf16* __restrict__ B,
                                                 const float* __restrict__ bias,
                                                 __bf16* __restrict__ C,
                                                 int M, int N, int K, int ldc) {
  const int z = blockIdx.z;
  const __bf16* Bz = B + (size_t)z * 1048576;
  const float* biasz = bias + z * 1024;
  const int coloffz = z * 1024;
  const int tm = blockIdx.x * 128, tn = blockIdx.y * 128;
  const int tid = threadIdx.x;
  const int w = tid >> 6, l = tid & 63;
  const int l15 = l & 15, l4 = l >> 4;
  const int wm = (w >> 1) * 64, wn = (w & 1) * 64;
  __shared__ __bf16 As[128][72];
  __shared__ __bf16 Bs[128][72];
  f32x4 acc[4][4] = {};
  for (int kt = 0; kt < K; kt += 64) {
    __syncthreads();
#pragma unroll
    for (int i = 0; i < 4; ++i) {
      int c = tid + i * 256;
      int r = c >> 3, s = (c & 7) * 8;
      *(bf16x8*)(&As[r][s]) = *(const bf16x8*)(A + (size_t)(tm + r) * K + kt + s);
    }
#pragma unroll
    for (int i = 0; i < 4; ++i) {
      int c = tid + i * 256;
      int kr = c >> 4, nc = (c & 15) * 8;
      bf16x8 bv = *(const bf16x8*)(Bz + (size_t)(kt + kr) * N + tn + nc);
#pragma unroll
      for (int j = 0; j < 8; ++j) Bs[nc + j][kr] = bv[j];
    }
    __syncthreads();
#pragma unroll
    for (int kk = 0; kk < 2; ++kk) {
      bf16x8 af[4], bfr[4];
#pragma unroll
      for (int m = 0; m < 4; ++m)
        af[m] = *(const bf16x8*)(&As[wm + m * 16 + l15][kk * 32 + l4 * 8]);
#pragma unroll
      for (int n = 0; n < 4; ++n)
        bfr[n] = *(const bf16x8*)(&Bs[wn + n * 16 + l15][kk * 32 + l4 * 8]);
#pragma unroll
      for (int m = 0; m < 4; ++m)
#pragma unroll
        for (int n = 0; n < 4; ++n)
          acc[m][n] = mfma16(af[m], bfr[n], acc[m][n]);
    }
  }
#pragma unroll
  for (int m = 0; m < 4; ++m)
#pragma unroll
    for (int n = 0; n < 4; ++n) {
      int row = tm + wm + m * 16 + l4 * 4;
      int col = tn + wn + n * 16 + l15;
      float bb = biasz[col];
#pragma unroll
      for (int r = 0; r < 4; ++r)
        C[(size_t)(row + r) * ldc + coloffz + col] = (__bf16)(acc[m][n][r] + bb);
    }
}

// Output projection: A rows are comb2 (pair-local); stores at pairOff in d_out.
__global__ __launch_bounds__(256) void gemm_nt_out_k(const __bf16* __restrict__ A,
                                                     const __bf16* __restrict__ B,
                                                     const float* __restrict__ bias,
                                                     void* __restrict__ out,
                                                     int M, int N, int K, int pairOff,
                                                     const int* __restrict__ flag) {
  const int tm = blockIdx.x * 128, tn = blockIdx.y * 128;
  const int tid = threadIdx.x;
  const int w = tid >> 6, l = tid & 63;
  const int l15 = l & 15, l4 = l >> 4;
  const int wm = (w >> 1) * 64, wn = (w & 1) * 64;
  __shared__ __bf16 As[128][72];
  __shared__ __bf16 Bs[128][72];
  f32x4 acc[4][4] = {};
  for (int kt = 0; kt < K; kt += 64) {
    __syncthreads();
#pragma unroll
    for (int i = 0; i < 4; ++i) {
      int c = tid + i * 256;
      int r = c >> 3, s = (c & 7) * 8;
      *(bf16x8*)(&As[r][s]) = *(const bf16x8*)(A + (size_t)(tm + r) * K + kt + s);
    }
#pragma unroll
    for (int i = 0; i < 4; ++i) {
      int c = tid + i * 256;
      int kr = c >> 4, nc = (c & 15) * 8;
      bf16x8 bv = *(const bf16x8*)(B + (size_t)(kt + kr) * N + tn + nc);
#pragma unroll
      for (int j = 0; j < 8; ++j) Bs[nc + j][kr] = bv[j];
    }
    __syncthreads();
#pragma unroll
    for (int kk = 0; kk < 2; ++kk) {
      bf16x8 af[4], bfr[4];
#pragma unroll
      for (int m = 0; m < 4; ++m)
        af[m] = *(const bf16x8*)(&As[wm + m * 16 + l15][kk * 32 + l4 * 8]);
#pragma unroll
      for (int n = 0; n < 4; ++n)
        bfr[n] = *(const bf16x8*)(&Bs[wn + n * 16 + l15][kk * 32 + l4 * 8]);
#pragma unroll
      for (int m = 0; m < 4; ++m)
#pragma unroll
        for (int n = 0; n < 4; ++n)
          acc[m][n] = mfma16(af[m], bfr[n], acc[m][n]);
    }
  }
  int use16 = *flag;
#pragma unroll
  for (int m = 0; m < 4; ++m)
#pragma unroll
    for (int n = 0; n < 4; ++n) {
      int row = tm + wm + m * 16 + l4 * 4;
      int col = tn + wn + n * 16 + l15;
      float bb = bias[col];
#pragma unroll
      for (int r = 0; r < 4; ++r) {
        float v = acc[m][n][r] + bb;
        size_t idx = (size_t)(pairOff + row + r) * N + col;
        if (use16) ((__bf16*)out)[idx] = (__bf16)v;
        else       ((float*)out)[idx] = v;
      }
    }
}

// ---------------- MFMA fused attention: batch-PAIR, RKb stride 66 ----------------
// QKV2 [2048][3072] bf16 in ws. grid (16 q-tiles, 32 = bl*16+h).
__global__ __launch_bounds__(256) void attn_fused_k(const __bf16* __restrict__ QKV2,
                                                    const float* __restrict__ amask,
                                                    const __bf16* __restrict__ rel16,
                                                    const __bf16* __restrict__ Mg16,
                                                    const float* __restrict__ zg32,
                                                    const float* __restrict__ ga32,
                                                    __bf16* __restrict__ comb) {
  const int qt = blockIdx.x, bh = blockIdx.y;
  const int bl = bh >> 4, h = bh & 15;
  const int tid = threadIdx.x;
  const int w = tid >> 6, l = tid & 63;
  const int l15 = l & 15, l4 = l >> 4;
  const int q0 = qt * 64;
  const __bf16* QKVb = QKV2 + (size_t)bl * 1024 * 3072;

  __shared__ __bf16 Kt[64][72];
  __shared__ __bf16 VtT[64][72];
  __shared__ __bf16 Pl[4][16 * 72];
  __shared__ float RKb[128 * 66];   // stride 66: kills the 16-way diagonal conflict
  __shared__ float maskv[64];
  __shared__ float denv[64];

  bf16x8 qf[2];
#pragma unroll
  for (int kk = 0; kk < 2; ++kk)
    qf[kk] = *(const bf16x8*)(QKVb + (size_t)(q0 + w * 16 + l15) * 3072 + h * 64 +
                              l4 * 8 + kk * 32);

  f32x4 accO[4] = {};
  float mrun[4], lrun[4];
#pragma unroll
  for (int r = 0; r < 4; ++r) { mrun[r] = -3.0e38f; lrun[r] = 0.f; }

  for (int kt = 0; kt < 16; ++kt) {
    const int k0 = kt * 64;
    __syncthreads();
#pragma unroll
    for (int i = 0; i < 2; ++i) {
      int c = tid + i * 256;
      int kr = c >> 3, s = (c & 7) * 8;
      const __bf16* src = QKVb + (size_t)(k0 + kr) * 3072 + h * 64;
      *(bf16x8*)(&Kt[kr][s]) = *(const bf16x8*)(src + 1024 + s);
      bf16x8 vv = *(const bf16x8*)(src + 2048 + s);
#pragma unroll
      for (int j = 0; j < 8; ++j) VtT[s + j][kr] = vv[j];
    }
    if (tid < 64) maskv[tid] = amask[bl * 1024 + k0 + tid];
    __syncthreads();

    const int jb = q0 - k0 - 63 + 1024;
#pragma unroll
    for (int ms = 0; ms < 2; ++ms) {
      f32x4 rk[4] = {};
#pragma unroll
      for (int kk = 0; kk < 2; ++kk) {
        bf16x8 ea = *(const bf16x8*)(rel16 + (size_t)(jb + w * 32 + ms * 16 + l15) * 64 +
                                     l4 * 8 + kk * 32);
#pragma unroll
        for (int nb = 0; nb < 4; ++nb) {
          bf16x8 kb = *(const bf16x8*)(&Kt[nb * 16 + l15][l4 * 8 + kk * 32]);
          rk[nb] = mfma16(ea, kb, rk[nb]);
        }
      }
#pragma unroll
      for (int nb = 0; nb < 4; ++nb)
#pragma unroll
        for (int r = 0; r < 4; ++r)
          RKb[(w * 32 + ms * 16 + l4 * 4 + r) * 66 + nb * 16 + l15] = rk[nb][r];
    }
    __syncthreads();

    f32x4 sacc[4] = {};
#pragma unroll
    for (int kk = 0; kk < 2; ++kk)
#pragma unroll
      for (int nb = 0; nb < 4; ++nb) {
        bf16x8 kb = *(const bf16x8*)(&Kt[nb * 16 + l15][l4 * 8 + kk * 32]);
        sacc[nb] = mfma16(qf[kk], kb, sacc[nb]);
      }

    float p[4][4];
    float tmax[4];
#pragma unroll
    for (int r = 0; r < 4; ++r) tmax[r] = -3.0e38f;
#pragma unroll
    for (int nb = 0; nb < 4; ++nb) {
      int kloc = nb * 16 + l15;
      float mk = maskv[kloc] * (-1e9f);
#pragma unroll
      for (int r = 0; r < 4; ++r) {
        int jl = (w * 16 + l4 * 4 + r) - kloc + 63;
        float s = (sacc[nb][r] + RKb[jl * 66 + kloc]) * 0.125f + mk;
        p[nb][r] = s;
        tmax[r] = fmaxf(tmax[r], s);
      }
    }
#pragma unroll
    for (int x = 1; x < 16; x <<= 1)
#pragma unroll
      for (int r = 0; r < 4; ++r) tmax[r] = fmaxf(tmax[r], __shfl_xor(tmax[r], x, 64));
    float al[4];
#pragma unroll
    for (int r = 0; r < 4; ++r) {
      float mn = fmaxf(mrun[r], tmax[r]);
      al[r] = __expf(mrun[r] - mn);
      mrun[r] = mn;
    }
    float rs[4] = {0.f, 0.f, 0.f, 0.f};
#pragma unroll
    for (int nb = 0; nb < 4; ++nb)
#pragma unroll
      for (int r = 0; r < 4; ++r) {
        p[nb][r] = __expf(p[nb][r] - mrun[r]);
        rs[r] += p[nb][r];
      }
#pragma unroll
    for (int x = 1; x < 16; x <<= 1)
#pragma unroll
      for (int r = 0; r < 4; ++r) rs[r] += __shfl_xor(rs[r], x, 64);
#pragma unroll
    for (int r = 0; r < 4; ++r) lrun[r] = lrun[r] * al[r] + rs[r];
#pragma unroll
    for (int nb = 0; nb < 4; ++nb)
#pragma unroll
      for (int r = 0; r < 4; ++r) accO[nb][r] *= al[r];

#pragma unroll
    for (int nb = 0; nb < 4; ++nb)
#pragma unroll
      for (int r = 0; r < 4; ++r)
        Pl[w][(l4 * 4 + r) * 72 + nb * 16 + l15] = (__bf16)p[nb][r];
    __syncthreads();

#pragma unroll
    for (int kk = 0; kk < 2; ++kk) {
      bf16x8 pa = *(const bf16x8*)(&Pl[w][l15 * 72 + kk * 32 + l4 * 8]);
#pragma unroll
      for (int nb = 0; nb < 4; ++nb) {
        bf16x8 vb = *(const bf16x8*)(&VtT[nb * 16 + l15][kk * 32 + l4 * 8]);
        accO[nb] = mfma16(pa, vb, accO[nb]);
      }
    }
  }

#pragma unroll
  for (int nb = 0; nb < 4; ++nb)
#pragma unroll
    for (int r = 0; r < 4; ++r) accO[nb][r] /= lrun[r];

  // ---- epilogue (overlays RKb) ----
  __syncthreads();
  __bf16* sqb = (__bf16*)RKb;
  __bf16* Mtb = ((__bf16*)RKb) + 64 * 72;
#pragma unroll
  for (int i = 0; i < 2; ++i) {
    int c = tid + i * 256;
    int qr = c >> 3, s = (c & 7) * 8;
    bf16x8 qv = *(const bf16x8*)(QKVb + (size_t)(q0 + qr) * 3072 + h * 64 + s);
#pragma unroll
    for (int j = 0; j < 8; ++j) {
      float x = (float)qv[j];
      sqb[qr * 72 + s + j] = (__bf16)(x > 0.f ? x + 1.f : __expf(x));
    }
    bf16x8 mv = *(const bf16x8*)(Mg16 + (size_t)h * 4096 + qr * 64 + s);
#pragma unroll
    for (int j = 0; j < 8; ++j) Mtb[(s + j) * 72 + qr] = mv[j];
  }
  __syncthreads();
  if (tid < 64) {
    float sden = 0.f;
    const float* zp = zg32 + h * 64;
#pragma unroll
    for (int d = 0; d < 64; ++d) sden += (float)sqb[tid * 72 + d] * zp[d];
    denv[tid] = sden + 1e-6f;
  }
  __syncthreads();
  float gate = 1.f / (1.f + __expf(-ga32[0]));
  f32x4 nacc[4] = {};
#pragma unroll
  for (int kk = 0; kk < 2; ++kk) {
    bf16x8 sa = *(const bf16x8*)(sqb + (w * 16 + l15) * 72 + kk * 32 + l4 * 8);
#pragma unroll
    for (int nb = 0; nb < 4; ++nb) {
      bf16x8 mb = *(const bf16x8*)(Mtb + (nb * 16 + l15) * 72 + kk * 32 + l4 * 8);
      nacc[nb] = mfma16(sa, mb, nacc[nb]);
    }
  }
#pragma unroll
  for (int nb = 0; nb < 4; ++nb)
#pragma unroll
    for (int r = 0; r < 4; ++r) {
      int qrel = w * 16 + l4 * 4 + r;
      float gl = nacc[nb][r] / denv[qrel];
      float cv = gate * accO[nb][r] + (1.f - gate) * gl;
      comb[(size_t)(bl * 1024 + q0 + qrel) * 1024 + h * 64 + nb * 16 + l15] = (__bf16)cv;
    }
}

// ---------------- launcher ----------------
extern "C" void kernel_launch(void* const* d_in, const int* in_sizes, int n_in,
                              void* d_out, int out_size, void* d_ws, size_t ws_size,
                              hipStream_t stream) {
  const int expect[14] = {4194304, 4096, 1048576, 1024, 1048576, 1024, 1048576,
                          1024, 1048576, 1024, 131136, 65536, 1024, 1};
  if (n_in != 14) return;
  for (int i = 0; i < 14; ++i)
    if (in_sizes[i] != expect[i]) return;

  char* ws = (char*)d_ws;
  int*    flag  = (int*)ws;                      // 4B
  float*  am32  = (float*)(ws + 1024);           // [4096]
  float*  b32   = (float*)(ws + 17408);          // bq|bk|bv|bo  [4][1024]
  float*  zg32  = (float*)(ws + 33792);          // [1024]
  float*  ga32  = (float*)(ws + 37888);          // [1]
  __bf16* Mg16  = (__bf16*)(ws + 38912);         // [65536] bf16
  __bf16* rel16 = (__bf16*)(ws + 301056);        // [131136]
  __bf16* hs16  = (__bf16*)(ws + 565248);        // [4096][1024] ends 8953856
  __bf16* W16   = (__bf16*)(ws + 8953856);       // 4x [1024][1024] ends 17342464
  __bf16* qkv2  = (__bf16*)(ws + 17342464);      // [2048][3072] ends 29925376
  __bf16* comb2 = (__bf16*)(ws + 29925376);      // [2048][1024] ends 34119680 (proven)

  detect_k<<<1, 256, 0, stream>>>((const uint32_t*)d_in[0], flag);

  cvt_to_bf16_k<<<16384, 256, 0, stream>>>(d_in[0], hs16, 4194304, flag);
  cvt_to_f32_k<<<16, 256, 0, stream>>>(d_in[1], am32, 4096, flag);
  const int widx[4] = {2, 4, 6, 8};
  for (int j = 0; j < 4; ++j) {
    cvt_to_bf16_k<<<4096, 256, 0, stream>>>(d_in[widx[j]], W16 + (size_t)j * 1048576,
                                            1048576, flag);
    cvt_to_f32_k<<<4, 256, 0, stream>>>(d_in[widx[j] + 1], b32 + j * 1024, 1024, flag);
  }
  cvt_to_bf16_k<<<513, 256, 0, stream>>>(d_in[10], rel16, 131136, flag);
  cvt_to_bf16_k<<<256, 256, 0, stream>>>(d_in[11], Mg16, 65536, flag);
  cvt_to_f32_k<<<4, 256, 0, stream>>>(d_in[12], zg32, 1024, flag);
  cvt_to_f32_k<<<1, 256, 0, stream>>>(d_in[13], ga32, 1, flag);

  for (int pr = 0; pr < 2; ++pr) {
    // paired QKV projection: M=2048 rows (two batches, contiguous in hs16)
    gemm_nt_k<<<dim3(16, 8, 3), 256, 0, stream>>>(
        hs16 + (size_t)pr * 2097152, W16, b32, qkv2, 2048, 1024, 1024, 3072);
    // paired fused attention (2 blocks/CU)
    attn_fused_k<<<dim3(16, 32), 256, 0, stream>>>(
        qkv2, am32 + pr * 2048, rel16, Mg16, zg32, ga32, comb2);
    // paired output projection -> d_out rows [pr*2048, pr*2048+2048)
    gemm_nt_out_k<<<dim3(16, 8), 256, 0, stream>>>(
        comb2, W16 + 3 * 1048576, b32 + 3072, d_out, 2048, 1024, 1024, pr * 2048, flag);
  }
}

// Round 24
// 283.169 us; speedup vs baseline: 9.6832x; 1.5198x over previous
//
#include <hip/hip_runtime.h>
#include <cstdint>
#include <cstddef>

typedef __bf16 bf16x8 __attribute__((ext_vector_type(8)));
typedef float f32x4 __attribute__((ext_vector_type(4)));

static __device__ __forceinline__ f32x4 mfma16(bf16x8 a, bf16x8 b, f32x4 c) {
  return __builtin_amdgcn_mfma_f32_16x16x32_bf16(a, b, c, 0, 0, 0);
}

// LAW (R19/R20 proven): compute kernels must NEVER vector-load from d_in —
// d_in is only touched by scalar-load kernels; all bf16x8 loads hit ws.

// ---------------- input dtype sniffing (proven) ----------------
__global__ __launch_bounds__(256) void detect_k(const uint32_t* __restrict__ hs,
                                                int* __restrict__ flag) {
  __shared__ int cnt;
  if (threadIdx.x == 0) cnt = 0;
  __syncthreads();
  uint32_t w = hs[threadIdx.x];
  int b = (w >> 8) & 0x7F;
  if (b >= 0x3C && b <= 0x40) atomicAdd(&cnt, 1);
  __syncthreads();
  if (threadIdx.x == 0) *flag = (cnt >= 128) ? 1 : 0;
}

// ---------------- dtype-adaptive converters (proven; SCALAR d_in reads) ----------
__global__ __launch_bounds__(256) void cvt_to_bf16_k(const void* __restrict__ src,
                                                     __bf16* __restrict__ dst, int n,
                                                     const int* __restrict__ flag) {
  int i = blockIdx.x * 256 + threadIdx.x;
  if (i >= n) return;
  float v = (*flag) ? (float)((const __bf16*)src)[i] : ((const float*)src)[i];
  dst[i] = (__bf16)v;
}

__global__ __launch_bounds__(256) void cvt_to_f32_k(const void* __restrict__ src,
                                                    float* __restrict__ dst, int n,
                                                    const int* __restrict__ flag) {
  int i = blockIdx.x * 256 + threadIdx.x;
  if (i >= n) return;
  dst[i] = (*flag) ? (float)((const __bf16*)src)[i] : ((const float*)src)[i];
}

// Transposing weight converter: W (d_in, [1024][1024]) -> Wt[n][k] in ws.
// d_in reads are SCALAR (law); LDS 32x32 tile; ws writes coalesced along k.
__global__ void cvt_wT_k(const void* __restrict__ W, __bf16* __restrict__ T,
                         const int* __restrict__ flag) {
  __shared__ __bf16 t[32][33];
  int k0 = blockIdx.x * 32, n0 = blockIdx.y * 32;
  int tx = threadIdx.x, ty = threadIdx.y;
  int f = *flag;
#pragma unroll
  for (int i = 0; i < 32; i += 8) {
    size_t idx = (size_t)(k0 + ty + i) * 1024 + n0 + tx;
    float v = f ? (float)((const __bf16*)W)[idx] : ((const float*)W)[idx];
    t[ty + i][tx] = (__bf16)v;
  }
  __syncthreads();
#pragma unroll
  for (int i = 0; i < 32; i += 8)
    T[(size_t)(n0 + ty + i) * 1024 + k0 + tx] = t[tx][ty + i];
}

// ---------------- m92 XOR-swizzled GEMM: C = A[M][K] @ Bt[N][K]^T + bias ---------
// All-vector LDS staging (no transpose scatter). Frag/C-D conventions identical
// to the R21-proven gemm_nt_k; swizzle is self-consistent write/read.
__global__ __launch_bounds__(256) void gemm_bt_k(const __bf16* __restrict__ A,
                                                 const __bf16* __restrict__ Bt,
                                                 const float* __restrict__ bias,
                                                 __bf16* __restrict__ C,
                                                 int M, int N, int K, int ldc) {
  const int tm = blockIdx.x * 128, tn = blockIdx.y * 128;
  const int tid = threadIdx.x;
  const int w = tid >> 6, l = tid & 63;
  const int l15 = l & 15, l4 = l >> 4;
  const int wm = (w >> 1) * 64, wn = (w & 1) * 64;
  __shared__ __bf16 As[128 * 64];
  __shared__ __bf16 Bs[128 * 64];
  f32x4 acc[4][4] = {};
  for (int kt = 0; kt < K; kt += 64) {
    __syncthreads();
#pragma unroll
    for (int i = 0; i < 4; ++i) {
      int c = tid + i * 256;
      int r = c >> 3, s = c & 7;
      int byt = r * 128 + ((s ^ (r & 7)) << 4);
      *(bf16x8*)((char*)As + byt) = *(const bf16x8*)(A + (size_t)(tm + r) * K + kt + s * 8);
      *(bf16x8*)((char*)Bs + byt) = *(const bf16x8*)(Bt + (size_t)(tn + r) * K + kt + s * 8);
    }
    __syncthreads();
#pragma unroll
    for (int kk = 0; kk < 2; ++kk) {
      bf16x8 af[4], bfr[4];
#pragma unroll
      for (int m = 0; m < 4; ++m) {
        int row = wm + m * 16 + l15;
        af[m] = *(const bf16x8*)((char*)As + row * 128 + (((l4 + 4 * kk) ^ (row & 7)) << 4));
      }
#pragma unroll
      for (int n = 0; n < 4; ++n) {
        int row = wn + n * 16 + l15;
        bfr[n] = *(const bf16x8*)((char*)Bs + row * 128 + (((l4 + 4 * kk) ^ (row & 7)) << 4));
      }
#pragma unroll
      for (int m = 0; m < 4; ++m)
#pragma unroll
        for (int n = 0; n < 4; ++n)
          acc[m][n] = mfma16(af[m], bfr[n], acc[m][n]);
    }
  }
#pragma unroll
  for (int m = 0; m < 4; ++m)
#pragma unroll
    for (int n = 0; n < 4; ++n) {
      int row = tm + wm + m * 16 + l4 * 4;
      int col = tn + wn + n * 16 + l15;
      float bb = bias[col];
#pragma unroll
      for (int r = 0; r < 4; ++r)
        C[(size_t)(row + r) * ldc + col] = (__bf16)(acc[m][n][r] + bb);
    }
}

// Output-projection variant: dtype-branched store to d_out at pairOff.
__global__ __launch_bounds__(256) void gemm_bt_out_k(const __bf16* __restrict__ A,
                                                     const __bf16* __restrict__ Bt,
                                                     const float* __restrict__ bias,
                                                     void* __restrict__ out,
                                                     int M, int N, int K, int pairOff,
                                                     const int* __restrict__ flag) {
  const int tm = blockIdx.x * 128, tn = blockIdx.y * 128;
  const int tid = threadIdx.x;
  const int w = tid >> 6, l = tid & 63;
  const int l15 = l & 15, l4 = l >> 4;
  const int wm = (w >> 1) * 64, wn = (w & 1) * 64;
  __shared__ __bf16 As[128 * 64];
  __shared__ __bf16 Bs[128 * 64];
  f32x4 acc[4][4] = {};
  for (int kt = 0; kt < K; kt += 64) {
    __syncthreads();
#pragma unroll
    for (int i = 0; i < 4; ++i) {
      int c = tid + i * 256;
      int r = c >> 3, s = c & 7;
      int byt = r * 128 + ((s ^ (r & 7)) << 4);
      *(bf16x8*)((char*)As + byt) = *(const bf16x8*)(A + (size_t)(tm + r) * K + kt + s * 8);
      *(bf16x8*)((char*)Bs + byt) = *(const bf16x8*)(Bt + (size_t)(tn + r) * K + kt + s * 8);
    }
    __syncthreads();
#pragma unroll
    for (int kk = 0; kk < 2; ++kk) {
      bf16x8 af[4], bfr[4];
#pragma unroll
      for (int m = 0; m < 4; ++m) {
        int row = wm + m * 16 + l15;
        af[m] = *(const bf16x8*)((char*)As + row * 128 + (((l4 + 4 * kk) ^ (row & 7)) << 4));
      }
#pragma unroll
      for (int n = 0; n < 4; ++n) {
        int row = wn + n * 16 + l15;
        bfr[n] = *(const bf16x8*)((char*)Bs + row * 128 + (((l4 + 4 * kk) ^ (row & 7)) << 4));
      }
#pragma unroll
      for (int m = 0; m < 4; ++m)
#pragma unroll
        for (int n = 0; n < 4; ++n)
          acc[m][n] = mfma16(af[m], bfr[n], acc[m][n]);
    }
  }
  int use16 = *flag;
#pragma unroll
  for (int m = 0; m < 4; ++m)
#pragma unroll
    for (int n = 0; n < 4; ++n) {
      int row = tm + wm + m * 16 + l4 * 4;
      int col = tn + wn + n * 16 + l15;
      float bb = bias[col];
#pragma unroll
      for (int r = 0; r < 4; ++r) {
        float v = acc[m][n][r] + bb;
        size_t idx = (size_t)(pairOff + row + r) * N + col;
        if (use16) ((__bf16*)out)[idx] = (__bf16)v;
        else       ((float*)out)[idx] = v;
      }
    }
}

// ---------------- MFMA fused attention (R23-proven, verbatim) ----------------
__global__ __launch_bounds__(256) void attn_fused_k(const __bf16* __restrict__ QKV2,
                                                    const float* __restrict__ amask,
                                                    const __bf16* __restrict__ rel16,
                                                    const __bf16* __restrict__ Mg16,
                                                    const float* __restrict__ zg32,
                                                    const float* __restrict__ ga32,
                                                    __bf16* __restrict__ comb) {
  const int qt = blockIdx.x, bh = blockIdx.y;
  const int bl = bh >> 4, h = bh & 15;
  const int tid = threadIdx.x;
  const int w = tid >> 6, l = tid & 63;
  const int l15 = l & 15, l4 = l >> 4;
  const int q0 = qt * 64;
  const __bf16* QKVb = QKV2 + (size_t)bl * 1024 * 3072;

  __shared__ __bf16 Kt[64][72];
  __shared__ __bf16 VtT[64][72];
  __shared__ __bf16 Pl[4][16 * 72];
  __shared__ float RKb[128 * 66];
  __shared__ float maskv[64];
  __shared__ float denv[64];

  bf16x8 qf[2];
#pragma unroll
  for (int kk = 0; kk < 2; ++kk)
    qf[kk] = *(const bf16x8*)(QKVb + (size_t)(q0 + w * 16 + l15) * 3072 + h * 64 +
                              l4 * 8 + kk * 32);

  f32x4 accO[4] = {};
  float mrun[4], lrun[4];
#pragma unroll
  for (int r = 0; r < 4; ++r) { mrun[r] = -3.0e38f; lrun[r] = 0.f; }

  for (int kt = 0; kt < 16; ++kt) {
    const int k0 = kt * 64;
    __syncthreads();
#pragma unroll
    for (int i = 0; i < 2; ++i) {
      int c = tid + i * 256;
      int kr = c >> 3, s = (c & 7) * 8;
      const __bf16* src = QKVb + (size_t)(k0 + kr) * 3072 + h * 64;
      *(bf16x8*)(&Kt[kr][s]) = *(const bf16x8*)(src + 1024 + s);
      bf16x8 vv = *(const bf16x8*)(src + 2048 + s);
#pragma unroll
      for (int j = 0; j < 8; ++j) VtT[s + j][kr] = vv[j];
    }
    if (tid < 64) maskv[tid] = amask[bl * 1024 + k0 + tid];
    __syncthreads();

    const int jb = q0 - k0 - 63 + 1024;
#pragma unroll
    for (int ms = 0; ms < 2; ++ms) {
      f32x4 rk[4] = {};
#pragma unroll
      for (int kk = 0; kk < 2; ++kk) {
        bf16x8 ea = *(const bf16x8*)(rel16 + (size_t)(jb + w * 32 + ms * 16 + l15) * 64 +
                                     l4 * 8 + kk * 32);
#pragma unroll
        for (int nb = 0; nb < 4; ++nb) {
          bf16x8 kb = *(const bf16x8*)(&Kt[nb * 16 + l15][l4 * 8 + kk * 32]);
          rk[nb] = mfma16(ea, kb, rk[nb]);
        }
      }
#pragma unroll
      for (int nb = 0; nb < 4; ++nb)
#pragma unroll
        for (int r = 0; r < 4; ++r)
          RKb[(w * 32 + ms * 16 + l4 * 4 + r) * 66 + nb * 16 + l15] = rk[nb][r];
    }
    __syncthreads();

    f32x4 sacc[4] = {};
#pragma unroll
    for (int kk = 0; kk < 2; ++kk)
#pragma unroll
      for (int nb = 0; nb < 4; ++nb) {
        bf16x8 kb = *(const bf16x8*)(&Kt[nb * 16 + l15][l4 * 8 + kk * 32]);
        sacc[nb] = mfma16(qf[kk], kb, sacc[nb]);
      }

    float p[4][4];
    float tmax[4];
#pragma unroll
    for (int r = 0; r < 4; ++r) tmax[r] = -3.0e38f;
#pragma unroll
    for (int nb = 0; nb < 4; ++nb) {
      int kloc = nb * 16 + l15;
      float mk = maskv[kloc] * (-1e9f);
#pragma unroll
      for (int r = 0; r < 4; ++r) {
        int jl = (w * 16 + l4 * 4 + r) - kloc + 63;
        float s = (sacc[nb][r] + RKb[jl * 66 + kloc]) * 0.125f + mk;
        p[nb][r] = s;
        tmax[r] = fmaxf(tmax[r], s);
      }
    }
#pragma unroll
    for (int x = 1; x < 16; x <<= 1)
#pragma unroll
      for (int r = 0; r < 4; ++r) tmax[r] = fmaxf(tmax[r], __shfl_xor(tmax[r], x, 64));
    float al[4];
#pragma unroll
    for (int r = 0; r < 4; ++r) {
      float mn = fmaxf(mrun[r], tmax[r]);
      al[r] = __expf(mrun[r] - mn);
      mrun[r] = mn;
    }
    float rs[4] = {0.f, 0.f, 0.f, 0.f};
#pragma unroll
    for (int nb = 0; nb < 4; ++nb)
#pragma unroll
      for (int r = 0; r < 4; ++r) {
        p[nb][r] = __expf(p[nb][r] - mrun[r]);
        rs[r] += p[nb][r];
      }
#pragma unroll
    for (int x = 1; x < 16; x <<= 1)
#pragma unroll
      for (int r = 0; r < 4; ++r) rs[r] += __shfl_xor(rs[r], x, 64);
#pragma unroll
    for (int r = 0; r < 4; ++r) lrun[r] = lrun[r] * al[r] + rs[r];
#pragma unroll
    for (int nb = 0; nb < 4; ++nb)
#pragma unroll
      for (int r = 0; r < 4; ++r) accO[nb][r] *= al[r];

#pragma unroll
    for (int nb = 0; nb < 4; ++nb)
#pragma unroll
      for (int r = 0; r < 4; ++r)
        Pl[w][(l4 * 4 + r) * 72 + nb * 16 + l15] = (__bf16)p[nb][r];
    __syncthreads();

#pragma unroll
    for (int kk = 0; kk < 2; ++kk) {
      bf16x8 pa = *(const bf16x8*)(&Pl[w][l15 * 72 + kk * 32 + l4 * 8]);
#pragma unroll
      for (int nb = 0; nb < 4; ++nb) {
        bf16x8 vb = *(const bf16x8*)(&VtT[nb * 16 + l15][kk * 32 + l4 * 8]);
        accO[nb] = mfma16(pa, vb, accO[nb]);
      }
    }
  }

#pragma unroll
  for (int nb = 0; nb < 4; ++nb)
#pragma unroll
    for (int r = 0; r < 4; ++r) accO[nb][r] /= lrun[r];

  __syncthreads();
  __bf16* sqb = (__bf16*)RKb;
  __bf16* Mtb = ((__bf16*)RKb) + 64 * 72;
#pragma unroll
  for (int i = 0; i < 2; ++i) {
    int c = tid + i * 256;
    int qr = c >> 3, s = (c & 7) * 8;
    bf16x8 qv = *(const bf16x8*)(QKVb + (size_t)(q0 + qr) * 3072 + h * 64 + s);
#pragma unroll
    for (int j = 0; j < 8; ++j) {
      float x = (float)qv[j];
      sqb[qr * 72 + s + j] = (__bf16)(x > 0.f ? x + 1.f : __expf(x));
    }
    bf16x8 mv = *(const bf16x8*)(Mg16 + (size_t)h * 4096 + qr * 64 + s);
#pragma unroll
    for (int j = 0; j < 8; ++j) Mtb[(s + j) * 72 + qr] = mv[j];
  }
  __syncthreads();
  if (tid < 64) {
    float sden = 0.f;
    const float* zp = zg32 + h * 64;
#pragma unroll
    for (int d = 0; d < 64; ++d) sden += (float)sqb[tid * 72 + d] * zp[d];
    denv[tid] = sden + 1e-6f;
  }
  __syncthreads();
  float gate = 1.f / (1.f + __expf(-ga32[0]));
  f32x4 nacc[4] = {};
#pragma unroll
  for (int kk = 0; kk < 2; ++kk) {
    bf16x8 sa = *(const bf16x8*)(sqb + (w * 16 + l15) * 72 + kk * 32 + l4 * 8);
#pragma unroll
    for (int nb = 0; nb < 4; ++nb) {
      bf16x8 mb = *(const bf16x8*)(Mtb + (nb * 16 + l15) * 72 + kk * 32 + l4 * 8);
      nacc[nb] = mfma16(sa, mb, nacc[nb]);
    }
  }
#pragma unroll
  for (int nb = 0; nb < 4; ++nb)
#pragma unroll
    for (int r = 0; r < 4; ++r) {
      int qrel = w * 16 + l4 * 4 + r;
      float gl = nacc[nb][r] / denv[qrel];
      float cv = gate * accO[nb][r] + (1.f - gate) * gl;
      comb[(size_t)(bl * 1024 + q0 + qrel) * 1024 + h * 64 + nb * 16 + l15] = (__bf16)cv;
    }
}

// ---------------- launcher ----------------
extern "C" void kernel_launch(void* const* d_in, const int* in_sizes, int n_in,
                              void* d_out, int out_size, void* d_ws, size_t ws_size,
                              hipStream_t stream) {
  const int expect[14] = {4194304, 4096, 1048576, 1024, 1048576, 1024, 1048576,
                          1024, 1048576, 1024, 131136, 65536, 1024, 1};
  if (n_in != 14) return;
  for (int i = 0; i < 14; ++i)
    if (in_sizes[i] != expect[i]) return;

  char* ws = (char*)d_ws;
  int*    flag  = (int*)ws;                      // 4B
  float*  am32  = (float*)(ws + 1024);           // [4096]
  float*  b32   = (float*)(ws + 17408);          // bq|bk|bv|bo  [4][1024]
  float*  zg32  = (float*)(ws + 33792);          // [1024]
  float*  ga32  = (float*)(ws + 37888);          // [1]
  __bf16* Mg16  = (__bf16*)(ws + 38912);         // [65536] bf16
  __bf16* rel16 = (__bf16*)(ws + 301056);        // [131136]
  __bf16* hs16  = (__bf16*)(ws + 565248);        // [4096][1024] ends 8953856
  __bf16* WT16  = (__bf16*)(ws + 8953856);       // WqT|WkT|WvT|WoT [n][k], ends 17342464
  __bf16* qkv2  = (__bf16*)(ws + 17342464);      // [2048][3072] ends 29925376
  __bf16* comb2 = (__bf16*)(ws + 29925376);      // [2048][1024] ends 34119680 (proven)

  detect_k<<<1, 256, 0, stream>>>((const uint32_t*)d_in[0], flag);

  cvt_to_bf16_k<<<16384, 256, 0, stream>>>(d_in[0], hs16, 4194304, flag);
  cvt_to_f32_k<<<16, 256, 0, stream>>>(d_in[1], am32, 4096, flag);
  const int widx[4] = {2, 4, 6, 8};
  for (int j = 0; j < 4; ++j) {
    cvt_wT_k<<<dim3(32, 32), dim3(32, 8), 0, stream>>>(d_in[widx[j]],
                                                       WT16 + (size_t)j * 1048576, flag);
    cvt_to_f32_k<<<4, 256, 0, stream>>>(d_in[widx[j] + 1], b32 + j * 1024, 1024, flag);
  }
  cvt_to_bf16_k<<<513, 256, 0, stream>>>(d_in[10], rel16, 131136, flag);
  cvt_to_bf16_k<<<256, 256, 0, stream>>>(d_in[11], Mg16, 65536, flag);
  cvt_to_f32_k<<<4, 256, 0, stream>>>(d_in[12], zg32, 1024, flag);
  cvt_to_f32_k<<<1, 256, 0, stream>>>(d_in[13], ga32, 1, flag);

  for (int pr = 0; pr < 2; ++pr) {
    // paired QKV projection: Bt = WqT|WkT|WvT as one [3072][1024] operand
    gemm_bt_k<<<dim3(16, 24), 256, 0, stream>>>(
        hs16 + (size_t)pr * 2097152, WT16, b32, qkv2, 2048, 3072, 1024, 3072);
    attn_fused_k<<<dim3(16, 32), 256, 0, stream>>>(
        qkv2, am32 + pr * 2048, rel16, Mg16, zg32, ga32, comb2);
    gemm_bt_out_k<<<dim3(16, 8), 256, 0, stream>>>(
        comb2, WT16 + 3 * 1048576, b32 + 3072, d_out, 2048, 1024, 1024,
        pr * 2048, flag);
  }
}

// Round 25
// 270.933 us; speedup vs baseline: 10.1206x; 1.0452x over previous
//
#include <hip/hip_runtime.h>
#include <cstdint>
#include <cstddef>

typedef __bf16 bf16x8 __attribute__((ext_vector_type(8)));
typedef float f32x4 __attribute__((ext_vector_type(4)));

static __device__ __forceinline__ f32x4 mfma16(bf16x8 a, bf16x8 b, f32x4 c) {
  return __builtin_amdgcn_mfma_f32_16x16x32_bf16(a, b, c, 0, 0, 0);
}

// LAW (R19/R20 proven): compute kernels must NEVER vector-load from d_in —
// d_in is only touched by scalar-load kernels; all bf16x8 loads hit ws.

// ---------------- input dtype sniffing (proven) ----------------
__global__ __launch_bounds__(256) void detect_k(const uint32_t* __restrict__ hs,
                                                int* __restrict__ flag) {
  __shared__ int cnt;
  if (threadIdx.x == 0) cnt = 0;
  __syncthreads();
  uint32_t w = hs[threadIdx.x];
  int b = (w >> 8) & 0x7F;
  if (b >= 0x3C && b <= 0x40) atomicAdd(&cnt, 1);
  __syncthreads();
  if (threadIdx.x == 0) *flag = (cnt >= 128) ? 1 : 0;
}

// ---------------- dtype-adaptive converters (proven; SCALAR d_in reads) ----------
__global__ __launch_bounds__(256) void cvt_to_bf16_k(const void* __restrict__ src,
                                                     size_t srcOff,
                                                     __bf16* __restrict__ dst, int n,
                                                     const int* __restrict__ flag) {
  int i = blockIdx.x * 256 + threadIdx.x;
  if (i >= n) return;
  float v = (*flag) ? (float)((const __bf16*)src)[srcOff + i]
                    : ((const float*)src)[srcOff + i];
  dst[i] = (__bf16)v;
}

__global__ __launch_bounds__(256) void cvt_to_f32_k(const void* __restrict__ src,
                                                    float* __restrict__ dst, int n,
                                                    const int* __restrict__ flag) {
  int i = blockIdx.x * 256 + threadIdx.x;
  if (i >= n) return;
  dst[i] = (*flag) ? (float)((const __bf16*)src)[i] : ((const float*)src)[i];
}

// MgT[h][e][d] = M[h][d][e]  (scalar d_in reads; coalesced ws writes)
__global__ __launch_bounds__(256) void cvt_MgT_k(const void* __restrict__ src,
                                                 __bf16* __restrict__ dst,
                                                 const int* __restrict__ flag) {
  int i = blockIdx.x * 256 + threadIdx.x;
  if (i >= 65536) return;
  int h = i >> 12, rem = i & 4095, e = rem >> 6, d = rem & 63;
  size_t sidx = (size_t)h * 4096 + d * 64 + e;
  float v = (*flag) ? (float)((const __bf16*)src)[sidx] : ((const float*)src)[sidx];
  dst[i] = (__bf16)v;
}

// Transposing weight converter (R24-proven): W -> Wt[n][k] in ws.
__global__ void cvt_wT_k(const void* __restrict__ W, __bf16* __restrict__ T,
                         const int* __restrict__ flag) {
  __shared__ __bf16 t[32][33];
  int k0 = blockIdx.x * 32, n0 = blockIdx.y * 32;
  int tx = threadIdx.x, ty = threadIdx.y;
  int f = *flag;
#pragma unroll
  for (int i = 0; i < 32; i += 8) {
    size_t idx = (size_t)(k0 + ty + i) * 1024 + n0 + tx;
    float v = f ? (float)((const __bf16*)W)[idx] : ((const float*)W)[idx];
    t[ty + i][tx] = (__bf16)v;
  }
  __syncthreads();
#pragma unroll
  for (int i = 0; i < 32; i += 8)
    T[(size_t)(n0 + ty + i) * 1024 + k0 + tx] = t[tx][ty + i];
}

// ---------------- V transpose to global (R12-proven pattern) ----------------
// Vt2[bl][h][d][k] = qkv2[bl*1024 + k][2048 + h*64 + d]. grid (16 h, 16 kblk, 2 bl).
__global__ __launch_bounds__(256) void vt2_k(const __bf16* __restrict__ qkv2,
                                             __bf16* __restrict__ Vt2) {
  __shared__ __bf16 t[64][72];
  const int h = blockIdx.x, k0 = blockIdx.y * 64, bl = blockIdx.z;
  const int tid = threadIdx.x;
  const int r = tid >> 2, dc = (tid & 3) * 16;
  const __bf16* src = qkv2 + (size_t)(bl * 1024 + k0 + r) * 3072 + 2048 + h * 64 + dc;
  *(bf16x8*)(&t[r][dc]) = *(const bf16x8*)(src);
  *(bf16x8*)(&t[r][dc + 8]) = *(const bf16x8*)(src + 8);
  __syncthreads();
  const int dr = tid >> 2, kc = (tid & 3) * 16;
  __bf16* dst = Vt2 + ((size_t)(bl * 16 + h) * 64 + dr) * 1024 + k0 + kc;
  bf16x8 o0, o1;
#pragma unroll
  for (int j = 0; j < 8; ++j) { o0[j] = t[kc + j][dr]; o1[j] = t[kc + 8 + j][dr]; }
  *(bf16x8*)dst = o0;
  *(bf16x8*)(dst + 8) = o1;
}

// ---------------- m92 XOR-swizzled GEMM (R24-proven) ----------------
__global__ __launch_bounds__(256) void gemm_bt_k(const __bf16* __restrict__ A,
                                                 const __bf16* __restrict__ Bt,
                                                 const float* __restrict__ bias,
                                                 __bf16* __restrict__ C,
                                                 int M, int N, int K, int ldc) {
  const int tm = blockIdx.x * 128, tn = blockIdx.y * 128;
  const int tid = threadIdx.x;
  const int w = tid >> 6, l = tid & 63;
  const int l15 = l & 15, l4 = l >> 4;
  const int wm = (w >> 1) * 64, wn = (w & 1) * 64;
  __shared__ __bf16 As[128 * 64];
  __shared__ __bf16 Bs[128 * 64];
  f32x4 acc[4][4] = {};
  for (int kt = 0; kt < K; kt += 64) {
    __syncthreads();
#pragma unroll
    for (int i = 0; i < 4; ++i) {
      int c = tid + i * 256;
      int r = c >> 3, s = c & 7;
      int byt = r * 128 + ((s ^ (r & 7)) << 4);
      *(bf16x8*)((char*)As + byt) = *(const bf16x8*)(A + (size_t)(tm + r) * K + kt + s * 8);
      *(bf16x8*)((char*)Bs + byt) = *(const bf16x8*)(Bt + (size_t)(tn + r) * K + kt + s * 8);
    }
    __syncthreads();
#pragma unroll
    for (int kk = 0; kk < 2; ++kk) {
      bf16x8 af[4], bfr[4];
#pragma unroll
      for (int m = 0; m < 4; ++m) {
        int row = wm + m * 16 + l15;
        af[m] = *(const bf16x8*)((char*)As + row * 128 + (((l4 + 4 * kk) ^ (row & 7)) << 4));
      }
#pragma unroll
      for (int n = 0; n < 4; ++n) {
        int row = wn + n * 16 + l15;
        bfr[n] = *(const bf16x8*)((char*)Bs + row * 128 + (((l4 + 4 * kk) ^ (row & 7)) << 4));
      }
#pragma unroll
      for (int m = 0; m < 4; ++m)
#pragma unroll
        for (int n = 0; n < 4; ++n)
          acc[m][n] = mfma16(af[m], bfr[n], acc[m][n]);
    }
  }
#pragma unroll
  for (int m = 0; m < 4; ++m)
#pragma unroll
    for (int n = 0; n < 4; ++n) {
      int row = tm + wm + m * 16 + l4 * 4;
      int col = tn + wn + n * 16 + l15;
      float bb = bias[col];
#pragma unroll
      for (int r = 0; r < 4; ++r)
        C[(size_t)(row + r) * ldc + col] = (__bf16)(acc[m][n][r] + bb);
    }
}

__global__ __launch_bounds__(256) void gemm_bt_out_k(const __bf16* __restrict__ A,
                                                     const __bf16* __restrict__ Bt,
                                                     const float* __restrict__ bias,
                                                     void* __restrict__ out,
                                                     int M, int N, int K, int pairOff,
                                                     const int* __restrict__ flag) {
  const int tm = blockIdx.x * 128, tn = blockIdx.y * 128;
  const int tid = threadIdx.x;
  const int w = tid >> 6, l = tid & 63;
  const int l15 = l & 15, l4 = l >> 4;
  const int wm = (w >> 1) * 64, wn = (w & 1) * 64;
  __shared__ __bf16 As[128 * 64];
  __shared__ __bf16 Bs[128 * 64];
  f32x4 acc[4][4] = {};
  for (int kt = 0; kt < K; kt += 64) {
    __syncthreads();
#pragma unroll
    for (int i = 0; i < 4; ++i) {
      int c = tid + i * 256;
      int r = c >> 3, s = c & 7;
      int byt = r * 128 + ((s ^ (r & 7)) << 4);
      *(bf16x8*)((char*)As + byt) = *(const bf16x8*)(A + (size_t)(tm + r) * K + kt + s * 8);
      *(bf16x8*)((char*)Bs + byt) = *(const bf16x8*)(Bt + (size_t)(tn + r) * K + kt + s * 8);
    }
    __syncthreads();
#pragma unroll
    for (int kk = 0; kk < 2; ++kk) {
      bf16x8 af[4], bfr[4];
#pragma unroll
      for (int m = 0; m < 4; ++m) {
        int row = wm + m * 16 + l15;
        af[m] = *(const bf16x8*)((char*)As + row * 128 + (((l4 + 4 * kk) ^ (row & 7)) << 4));
      }
#pragma unroll
      for (int n = 0; n < 4; ++n) {
        int row = wn + n * 16 + l15;
        bfr[n] = *(const bf16x8*)((char*)Bs + row * 128 + (((l4 + 4 * kk) ^ (row & 7)) << 4));
      }
#pragma unroll
      for (int m = 0; m < 4; ++m)
#pragma unroll
        for (int n = 0; n < 4; ++n)
          acc[m][n] = mfma16(af[m], bfr[n], acc[m][n]);
    }
  }
  int use16 = *flag;
#pragma unroll
  for (int m = 0; m < 4; ++m)
#pragma unroll
    for (int n = 0; n < 4; ++n) {
      int row = tm + wm + m * 16 + l4 * 4;
      int col = tn + wn + n * 16 + l15;
      float bb = bias[col];
#pragma unroll
      for (int r = 0; r < 4; ++r) {
        float v = acc[m][n][r] + bb;
        size_t idx = (size_t)(pairOff + row + r) * N + col;
        if (use16) ((__bf16*)out)[idx] = (__bf16)v;
        else       ((float*)out)[idx] = v;
      }
    }
}

// ---------------- MFMA fused attention: vector-only LDS staging ----------------
// VtT staged from pre-transposed Vt2 (vector copies); Mtb from MgT16 (vector).
__global__ __launch_bounds__(256) void attn_fused_k(const __bf16* __restrict__ QKV2,
                                                    const __bf16* __restrict__ Vt2,
                                                    const float* __restrict__ amask,
                                                    const __bf16* __restrict__ rel16,
                                                    const __bf16* __restrict__ MgT16,
                                                    const float* __restrict__ zg32,
                                                    const float* __restrict__ ga32,
                                                    __bf16* __restrict__ comb) {
  const int qt = blockIdx.x, bh = blockIdx.y;
  const int bl = bh >> 4, h = bh & 15;
  const int tid = threadIdx.x;
  const int w = tid >> 6, l = tid & 63;
  const int l15 = l & 15, l4 = l >> 4;
  const int q0 = qt * 64;
  const __bf16* QKVb = QKV2 + (size_t)bl * 1024 * 3072;
  const __bf16* VtH = Vt2 + (size_t)(bl * 16 + h) * 64 * 1024;

  __shared__ __bf16 Kt[64][72];
  __shared__ __bf16 VtT[64][72];
  __shared__ __bf16 Pl[4][16 * 72];
  __shared__ float RKb[128 * 66];
  __shared__ float maskv[64];
  __shared__ float denv[64];

  bf16x8 qf[2];
#pragma unroll
  for (int kk = 0; kk < 2; ++kk)
    qf[kk] = *(const bf16x8*)(QKVb + (size_t)(q0 + w * 16 + l15) * 3072 + h * 64 +
                              l4 * 8 + kk * 32);

  f32x4 accO[4] = {};
  float mrun[4], lrun[4];
#pragma unroll
  for (int r = 0; r < 4; ++r) { mrun[r] = -3.0e38f; lrun[r] = 0.f; }

  for (int kt = 0; kt < 16; ++kt) {
    const int k0 = kt * 64;
    __syncthreads();
    // K staging (vector) + V^T staging (vector, from Vt2)
#pragma unroll
    for (int i = 0; i < 2; ++i) {
      int c = tid + i * 256;
      int kr = c >> 3, s = (c & 7) * 8;
      *(bf16x8*)(&Kt[kr][s]) =
          *(const bf16x8*)(QKVb + (size_t)(k0 + kr) * 3072 + 1024 + h * 64 + s);
      *(bf16x8*)(&VtT[kr][s]) = *(const bf16x8*)(VtH + (size_t)kr * 1024 + k0 + s);
    }
    if (tid < 64) maskv[tid] = amask[bl * 1024 + k0 + tid];
    __syncthreads();

    const int jb = q0 - k0 - 63 + 1024;
#pragma unroll
    for (int ms = 0; ms < 2; ++ms) {
      f32x4 rk[4] = {};
#pragma unroll
      for (int kk = 0; kk < 2; ++kk) {
        bf16x8 ea = *(const bf16x8*)(rel16 + (size_t)(jb + w * 32 + ms * 16 + l15) * 64 +
                                     l4 * 8 + kk * 32);
#pragma unroll
        for (int nb = 0; nb < 4; ++nb) {
          bf16x8 kb = *(const bf16x8*)(&Kt[nb * 16 + l15][l4 * 8 + kk * 32]);
          rk[nb] = mfma16(ea, kb, rk[nb]);
        }
      }
#pragma unroll
      for (int nb = 0; nb < 4; ++nb)
#pragma unroll
        for (int r = 0; r < 4; ++r)
          RKb[(w * 32 + ms * 16 + l4 * 4 + r) * 66 + nb * 16 + l15] = rk[nb][r];
    }
    __syncthreads();

    f32x4 sacc[4] = {};
#pragma unroll
    for (int kk = 0; kk < 2; ++kk)
#pragma unroll
      for (int nb = 0; nb < 4; ++nb) {
        bf16x8 kb = *(const bf16x8*)(&Kt[nb * 16 + l15][l4 * 8 + kk * 32]);
        sacc[nb] = mfma16(qf[kk], kb, sacc[nb]);
      }

    float p[4][4];
    float tmax[4];
#pragma unroll
    for (int r = 0; r < 4; ++r) tmax[r] = -3.0e38f;
#pragma unroll
    for (int nb = 0; nb < 4; ++nb) {
      int kloc = nb * 16 + l15;
      float mk = maskv[kloc] * (-1e9f);
#pragma unroll
      for (int r = 0; r < 4; ++r) {
        int jl = (w * 16 + l4 * 4 + r) - kloc + 63;
        float s = (sacc[nb][r] + RKb[jl * 66 + kloc]) * 0.125f + mk;
        p[nb][r] = s;
        tmax[r] = fmaxf(tmax[r], s);
      }
    }
#pragma unroll
    for (int x = 1; x < 16; x <<= 1)
#pragma unroll
      for (int r = 0; r < 4; ++r) tmax[r] = fmaxf(tmax[r], __shfl_xor(tmax[r], x, 64));
    float al[4];
#pragma unroll
    for (int r = 0; r < 4; ++r) {
      float mn = fmaxf(mrun[r], tmax[r]);
      al[r] = __expf(mrun[r] - mn);
      mrun[r] = mn;
    }
    float rs[4] = {0.f, 0.f, 0.f, 0.f};
#pragma unroll
    for (int nb = 0; nb < 4; ++nb)
#pragma unroll
      for (int r = 0; r < 4; ++r) {
        p[nb][r] = __expf(p[nb][r] - mrun[r]);
        rs[r] += p[nb][r];
      }
#pragma unroll
    for (int x = 1; x < 16; x <<= 1)
#pragma unroll
      for (int r = 0; r < 4; ++r) rs[r] += __shfl_xor(rs[r], x, 64);
#pragma unroll
    for (int r = 0; r < 4; ++r) lrun[r] = lrun[r] * al[r] + rs[r];
#pragma unroll
    for (int nb = 0; nb < 4; ++nb)
#pragma unroll
      for (int r = 0; r < 4; ++r) accO[nb][r] *= al[r];

#pragma unroll
    for (int nb = 0; nb < 4; ++nb)
#pragma unroll
      for (int r = 0; r < 4; ++r)
        Pl[w][(l4 * 4 + r) * 72 + nb * 16 + l15] = (__bf16)p[nb][r];
    __syncthreads();

#pragma unroll
    for (int kk = 0; kk < 2; ++kk) {
      bf16x8 pa = *(const bf16x8*)(&Pl[w][l15 * 72 + kk * 32 + l4 * 8]);
#pragma unroll
      for (int nb = 0; nb < 4; ++nb) {
        bf16x8 vb = *(const bf16x8*)(&VtT[nb * 16 + l15][kk * 32 + l4 * 8]);
        accO[nb] = mfma16(pa, vb, accO[nb]);
      }
    }
  }

#pragma unroll
  for (int nb = 0; nb < 4; ++nb)
#pragma unroll
    for (int r = 0; r < 4; ++r) accO[nb][r] /= lrun[r];

  // ---- epilogue (overlays RKb); Mtb staged vector from MgT16 ----
  __syncthreads();
  __bf16* sqb = (__bf16*)RKb;
  __bf16* Mtb = ((__bf16*)RKb) + 64 * 72;
#pragma unroll
  for (int i = 0; i < 2; ++i) {
    int c = tid + i * 256;
    int qr = c >> 3, s = (c & 7) * 8;
    bf16x8 qv = *(const bf16x8*)(QKVb + (size_t)(q0 + qr) * 3072 + h * 64 + s);
#pragma unroll
    for (int j = 0; j < 8; ++j) {
      float x = (float)qv[j];
      sqb[qr * 72 + s + j] = (__bf16)(x > 0.f ? x + 1.f : __expf(x));
    }
    // Mtb[e][d] rows e=qr (wait: c covers 512 = 64 rows x 8 chunks)
    bf16x8 mv = *(const bf16x8*)(MgT16 + (size_t)h * 4096 + qr * 64 + s);
    *(bf16x8*)(&Mtb[qr * 72 + s]) = mv;
  }
  __syncthreads();
  if (tid < 64) {
    float sden = 0.f;
    const float* zp = zg32 + h * 64;
#pragma unroll
    for (int d = 0; d < 64; ++d) sden += (float)sqb[tid * 72 + d] * zp[d];
    denv[tid] = sden + 1e-6f;
  }
  __syncthreads();
  float gate = 1.f / (1.f + __expf(-ga32[0]));
  f32x4 nacc[4] = {};
#pragma unroll
  for (int kk = 0; kk < 2; ++kk) {
    bf16x8 sa = *(const bf16x8*)(sqb + (w * 16 + l15) * 72 + kk * 32 + l4 * 8);
#pragma unroll
    for (int nb = 0; nb < 4; ++nb) {
      bf16x8 mb = *(const bf16x8*)(Mtb + (nb * 16 + l15) * 72 + kk * 32 + l4 * 8);
      nacc[nb] = mfma16(sa, mb, nacc[nb]);
    }
  }
#pragma unroll
  for (int nb = 0; nb < 4; ++nb)
#pragma unroll
    for (int r = 0; r < 4; ++r) {
      int qrel = w * 16 + l4 * 4 + r;
      float gl = nacc[nb][r] / denv[qrel];
      float cv = gate * accO[nb][r] + (1.f - gate) * gl;
      comb[(size_t)(bl * 1024 + q0 + qrel) * 1024 + h * 64 + nb * 16 + l15] = (__bf16)cv;
    }
}

// ---------------- launcher ----------------
extern "C" void kernel_launch(void* const* d_in, const int* in_sizes, int n_in,
                              void* d_out, int out_size, void* d_ws, size_t ws_size,
                              hipStream_t stream) {
  const int expect[14] = {4194304, 4096, 1048576, 1024, 1048576, 1024, 1048576,
                          1024, 1048576, 1024, 131136, 65536, 1024, 1};
  if (n_in != 14) return;
  for (int i = 0; i < 14; ++i)
    if (in_sizes[i] != expect[i]) return;

  char* ws = (char*)d_ws;
  int*    flag   = (int*)ws;                     // 4B
  float*  am32   = (float*)(ws + 1024);          // [4096]
  float*  b32    = (float*)(ws + 17408);         // bq|bk|bv|bo  [4][1024]
  float*  zg32   = (float*)(ws + 33792);         // [1024]
  float*  ga32   = (float*)(ws + 37888);         // [1]
  __bf16* MgT16  = (__bf16*)(ws + 38912);        // [16][64][64] M^T, ends 169984
  __bf16* rel16  = (__bf16*)(ws + 301056);       // [131136], ends 563328
  __bf16* hs_pr  = (__bf16*)(ws + 565248);       // [2048][1024] per pair, ends 4759552
  __bf16* WT16   = (__bf16*)(ws + 4759552);      // 4x Wt [n][k], ends 13148160
  __bf16* qkv2   = (__bf16*)(ws + 13148160);     // [2048][3072], ends 25731072
  __bf16* comb2  = (__bf16*)(ws + 25731072);     // [2048][1024], ends 29925376
  __bf16* Vt2    = (__bf16*)(ws + 29925376);     // [2][16][64][1024], ends 34119680

  detect_k<<<1, 256, 0, stream>>>((const uint32_t*)d_in[0], flag);

  cvt_to_f32_k<<<16, 256, 0, stream>>>(d_in[1], am32, 4096, flag);
  const int widx[4] = {2, 4, 6, 8};
  for (int j = 0; j < 4; ++j) {
    cvt_wT_k<<<dim3(32, 32), dim3(32, 8), 0, stream>>>(d_in[widx[j]],
                                                       WT16 + (size_t)j * 1048576, flag);
    cvt_to_f32_k<<<4, 256, 0, stream>>>(d_in[widx[j] + 1], b32 + j * 1024, 1024, flag);
  }
  cvt_to_bf16_k<<<513, 256, 0, stream>>>(d_in[10], 0, rel16, 131136, flag);
  cvt_MgT_k<<<256, 256, 0, stream>>>(d_in[11], MgT16, flag);
  cvt_to_f32_k<<<4, 256, 0, stream>>>(d_in[12], zg32, 1024, flag);
  cvt_to_f32_k<<<1, 256, 0, stream>>>(d_in[13], ga32, 1, flag);

  for (int pr = 0; pr < 2; ++pr) {
    cvt_to_bf16_k<<<8192, 256, 0, stream>>>(d_in[0], (size_t)pr * 2097152, hs_pr,
                                            2097152, flag);
    gemm_bt_k<<<dim3(16, 24), 256, 0, stream>>>(hs_pr, WT16, b32, qkv2,
                                                2048, 3072, 1024, 3072);
    vt2_k<<<dim3(16, 16, 2), 256, 0, stream>>>(qkv2, Vt2);
    attn_fused_k<<<dim3(16, 32), 256, 0, stream>>>(
        qkv2, Vt2, am32 + pr * 2048, rel16, MgT16, zg32, ga32, comb2);
    gemm_bt_out_k<<<dim3(16, 8), 256, 0, stream>>>(
        comb2, WT16 + 3 * 1048576, b32 + 3072, d_out, 2048, 1024, 1024,
        pr * 2048, flag);
  }
}